// Round 3
// baseline (906.192 us; speedup 1.0000x reference)
//
#include <hip/hip_runtime.h>

typedef __attribute__((ext_vector_type(8))) short bf16x8;
typedef __attribute__((ext_vector_type(4))) float f32x4;

static constexpr int S = 4096;
static constexpr int E = 2048;
static constexpr int F = 8192;
static constexpr int NH = 16;
static constexpr int DH = 128;

__device__ __forceinline__ unsigned short f2bf(float f) {
  unsigned u = __builtin_bit_cast(unsigned, f);
  u += 0x7FFFu + ((u >> 16) & 1u);
  return (unsigned short)(u >> 16);
}

// async global->LDS, 16B per lane. LDS dest = wave-uniform base + lane*16.
__device__ __forceinline__ void async16(const unsigned short* g, unsigned short* l) {
  __builtin_amdgcn_global_load_lds(
      (const __attribute__((address_space(1))) unsigned int*)g,
      (__attribute__((address_space(3))) unsigned int*)l, 16, 0, 0);
}

// Race-proof sync primitives: the barrier itself is a compiler memory fence
// (asm volatile + "memory") so no ds_read/global_load_lds can be scheduled
// across a publish point (bare __builtin_amdgcn_s_barrier() is NOT a compiler
// fence -> round-2's intermittent divergence). sched_barrier(0) additionally
// pins register-only ops (rule #18: MFMA can hoist past asm waits).
#define BARRIER()                                     \
  do {                                                \
    asm volatile("s_barrier" ::: "memory");           \
    __builtin_amdgcn_sched_barrier(0);                \
  } while (0)
#define WAIT_LGKM0()                                  \
  do {                                                \
    asm volatile("s_waitcnt lgkmcnt(0)" ::: "memory");\
    __builtin_amdgcn_sched_barrier(0);                \
  } while (0)
#define WAIT_VM(n)                                    \
  do {                                                \
    __builtin_amdgcn_sched_barrier(0);                \
    asm volatile("s_waitcnt vmcnt(" #n ")" ::: "memory"); \
    __builtin_amdgcn_sched_barrier(0);                \
  } while (0)

// ---------------- elementwise fp32 -> bf16 ----------------
__global__ __launch_bounds__(256) void cvt_bf16_kernel(const float* __restrict__ src,
                                                       unsigned short* __restrict__ dst) {
  int i = (blockIdx.x * 256 + threadIdx.x) * 4;
  float4 v = *(const float4*)(src + i);
  ushort4 o;
  o.x = f2bf(v.x); o.y = f2bf(v.y); o.z = f2bf(v.z); o.w = f2bf(v.w);
  *(ushort4*)(dst + i) = o;
}

// ---------------- transpose + convert: src [R][C] fp32 -> dst [C][R] bf16 ----------------
__global__ __launch_bounds__(256) void transpose_cvt(const float* __restrict__ src,
                                                     unsigned short* __restrict__ dst,
                                                     const int Rr, const int Cc) {
  __shared__ float t[32][33];
  const int c0 = blockIdx.x * 32, r0 = blockIdx.y * 32;
  const int tx = threadIdx.x, ty = threadIdx.y;
#pragma unroll
  for (int i = 0; i < 4; ++i) {
    int r = ty + i * 8;
    t[r][tx] = src[(size_t)(r0 + r) * Cc + c0 + tx];
  }
  __syncthreads();
#pragma unroll
  for (int i = 0; i < 4; ++i) {
    int cr = ty + i * 8;
    dst[(size_t)(c0 + cr) * Rr + r0 + tx] = f2bf(t[tx][cr]);
  }
}

// ---------------- GEMM 256x256x64 4-phase (T2+T3+T4+T5, m201-template port).
// C[M][N] = A[M][K] * B^T[N][K], bf16 in. 512 threads = 8 waves (2M x 4N),
// per-wave 128x64 output = acc[8][4]. LDS 128KB: 2 dbuf x (256x64) x {A,B}.
// XOR piece-swizzle pp = p ^ (row&7): linear DMA dest + pre-swizzled global
// source, swizzled ds_read -> conflict-free b128 reads.
// Per K-tile 4 phases, one C-quadrant (16 MFMA) each. Stage order for tile t+1:
//   ph0: B r0,r1   ph1: B r2,r3   ph2: A r0,r2   ph3: A r1,r3
// Per-wave vmcnt ledger (steady state, 2 issues/phase):
//   ph1 pre-wait queue [A1,A3,B0,B1,B2,B3] -> vmcnt(4) retires A1,A3 (read at
//   ph2); ph3 pre-wait queue of 8 -> vmcnt(2) retires all but A1,A3 (read at
//   NEXT tile's ph2). Never vmcnt(0) in the steady-state loop (T4).
enum { EPI_QKV = 0, EPI_RELU = 1, EPI_OUT = 2 };

template <int EPI>
__global__ __launch_bounds__(512, 2) void gemm8(
    const unsigned short* __restrict__ A, const unsigned short* __restrict__ B,
    const int K, const int N,
    const float* __restrict__ b0, const float* __restrict__ b1f, const float* __restrict__ b2f,
    unsigned short* __restrict__ o0, unsigned short* __restrict__ o1,
    unsigned short* __restrict__ o2, float* __restrict__ of) {
  __shared__ unsigned short lA[2][256 * 64];
  __shared__ unsigned short lB[2][256 * 64];
  const int tid = threadIdx.x, w = tid >> 6, lane = tid & 63;
  const int lane15 = lane & 15, l4 = lane >> 4;
  const int wr = w >> 2, wc = w & 3;
  const int m0 = blockIdx.y * 256, n0 = blockIdx.x * 256;

  // staging: thread t covers physical (row = r*64 + (t>>3), piece pp = t&7) of
  // each 64-row round; conceptual piece fetched = pp ^ (row&7) (involution).
  const int prow = tid >> 3;
  const int pcc = (tid & 7) ^ (prow & 7);
  const unsigned short* gA = A + (size_t)(m0 + prow) * K + pcc * 8;
  const unsigned short* gB = B + (size_t)(n0 + prow) * K + pcc * 8;
  const size_t rstep = (size_t)64 * K;  // 64 rows
  const int lw = w * 512;               // wave slice within a 4096-ushort round

  // ds_read swizzled piece index for kk=0,1 (row&7 == lane15&7 for frag rows)
  const int pswz0 = l4 ^ (lane15 & 7);
  const int pswz1 = (4 + l4) ^ (lane15 & 7);
  const int arow = (wr * 128 + lane15) * 64;
  const int brow = (wc * 64 + lane15) * 64;

  f32x4 zero4 = {0.f, 0.f, 0.f, 0.f};
  f32x4 acc[8][4];
#pragma unroll
  for (int i = 0; i < 8; ++i)
#pragma unroll
    for (int j = 0; j < 4; ++j) acc[i][j] = zero4;

  // prologue: stage full tile 0 into buf 0, drain, publish
#pragma unroll
  for (int r = 0; r < 4; ++r) async16(gB + r * rstep, &lB[0][r * 4096 + lw]);
#pragma unroll
  for (int r = 0; r < 4; ++r) async16(gA + r * rstep, &lA[0][r * 4096 + lw]);
  WAIT_VM(0);
  BARRIER();

  const int NT = K >> 6;
  bf16x8 a0[4][2], bb[2][2];
  for (int t = 0; t < NT; ++t) {
    const unsigned short* lAb = lA[t & 1];
    const unsigned short* lBb = lB[t & 1];
    unsigned short* lAn = lA[(t & 1) ^ 1];
    unsigned short* lBn = lB[(t & 1) ^ 1];
    const size_t ko = (size_t)(t + 1) * 64;
    const bool nxt = (t + 1 < NT);

    // ======== phase 0: quadrant (mh=0, nh=0); stage B r0,r1 ========
#pragma unroll
    for (int mi = 0; mi < 4; ++mi) {
      a0[mi][0] = *(const bf16x8*)&lAb[arow + mi * 1024 + pswz0 * 8];
      a0[mi][1] = *(const bf16x8*)&lAb[arow + mi * 1024 + pswz1 * 8];
    }
#pragma unroll
    for (int nj = 0; nj < 2; ++nj) {
      bb[nj][0] = *(const bf16x8*)&lBb[brow + nj * 1024 + pswz0 * 8];
      bb[nj][1] = *(const bf16x8*)&lBb[brow + nj * 1024 + pswz1 * 8];
    }
    if (nxt) {
      async16(gB + 0 * rstep + ko, &lBn[0 * 4096 + lw]);
      async16(gB + 1 * rstep + ko, &lBn[1 * 4096 + lw]);
    }
    BARRIER();
    WAIT_LGKM0();
    __builtin_amdgcn_s_setprio(1);
#pragma unroll
    for (int mi = 0; mi < 4; ++mi)
#pragma unroll
      for (int nj = 0; nj < 2; ++nj)
#pragma unroll
        for (int kk = 0; kk < 2; ++kk)
          acc[mi][nj] = __builtin_amdgcn_mfma_f32_16x16x32_bf16(a0[mi][kk], bb[nj][kk], acc[mi][nj], 0, 0, 0);
    __builtin_amdgcn_s_setprio(0);
    BARRIER();

    // ======== phase 1: quadrant (mh=0, nh=1); stage B r2,r3; retire deferred A ========
#pragma unroll
    for (int nj = 0; nj < 2; ++nj) {
      bb[nj][0] = *(const bf16x8*)&lBb[brow + 2048 + nj * 1024 + pswz0 * 8];
      bb[nj][1] = *(const bf16x8*)&lBb[brow + 2048 + nj * 1024 + pswz1 * 8];
    }
    if (nxt) {
      async16(gB + 2 * rstep + ko, &lBn[2 * 4096 + lw]);
      async16(gB + 3 * rstep + ko, &lBn[3 * 4096 + lw]);
    }
    BARRIER();
    WAIT_LGKM0();
    __builtin_amdgcn_s_setprio(1);
#pragma unroll
    for (int mi = 0; mi < 4; ++mi)
#pragma unroll
      for (int nj = 0; nj < 2; ++nj)
#pragma unroll
        for (int kk = 0; kk < 2; ++kk)
          acc[mi][2 + nj] = __builtin_amdgcn_mfma_f32_16x16x32_bf16(a0[mi][kk], bb[nj][kk], acc[mi][2 + nj], 0, 0, 0);
    __builtin_amdgcn_s_setprio(0);
    if (nxt)
      WAIT_VM(4);  // retire prev-tile A r1,r3 (read at phase 2); keep this tile's 4 B
    else
      WAIT_VM(0);  // final tile: drain leftovers
    BARRIER();

    // ======== phase 2: quadrant (mh=1, nh=0); stage A r0,r2 ========
#pragma unroll
    for (int mi = 0; mi < 4; ++mi) {
      a0[mi][0] = *(const bf16x8*)&lAb[arow + 4096 + mi * 1024 + pswz0 * 8];
      a0[mi][1] = *(const bf16x8*)&lAb[arow + 4096 + mi * 1024 + pswz1 * 8];
    }
#pragma unroll
    for (int nj = 0; nj < 2; ++nj) {
      bb[nj][0] = *(const bf16x8*)&lBb[brow + nj * 1024 + pswz0 * 8];
      bb[nj][1] = *(const bf16x8*)&lBb[brow + nj * 1024 + pswz1 * 8];
    }
    if (nxt) {
      async16(gA + 0 * rstep + ko, &lAn[0 * 4096 + lw]);
      async16(gA + 2 * rstep + ko, &lAn[2 * 4096 + lw]);
    }
    BARRIER();
    WAIT_LGKM0();
    __builtin_amdgcn_s_setprio(1);
#pragma unroll
    for (int mi = 0; mi < 4; ++mi)
#pragma unroll
      for (int nj = 0; nj < 2; ++nj)
#pragma unroll
        for (int kk = 0; kk < 2; ++kk)
          acc[4 + mi][nj] = __builtin_amdgcn_mfma_f32_16x16x32_bf16(a0[mi][kk], bb[nj][kk], acc[4 + mi][nj], 0, 0, 0);
    __builtin_amdgcn_s_setprio(0);
    BARRIER();

    // ======== phase 3: quadrant (mh=1, nh=1); stage A r1,r3; boundary wait ========
#pragma unroll
    for (int nj = 0; nj < 2; ++nj) {
      bb[nj][0] = *(const bf16x8*)&lBb[brow + 2048 + nj * 1024 + pswz0 * 8];
      bb[nj][1] = *(const bf16x8*)&lBb[brow + 2048 + nj * 1024 + pswz1 * 8];
    }
    if (nxt) {
      async16(gA + 1 * rstep + ko, &lAn[1 * 4096 + lw]);
      async16(gA + 3 * rstep + ko, &lAn[3 * 4096 + lw]);
    }
    BARRIER();
    WAIT_LGKM0();
    __builtin_amdgcn_s_setprio(1);
#pragma unroll
    for (int mi = 0; mi < 4; ++mi)
#pragma unroll
      for (int nj = 0; nj < 2; ++nj)
#pragma unroll
        for (int kk = 0; kk < 2; ++kk)
          acc[4 + mi][2 + nj] = __builtin_amdgcn_mfma_f32_16x16x32_bf16(a0[mi][kk], bb[nj][kk], acc[4 + mi][2 + nj], 0, 0, 0);
    __builtin_amdgcn_s_setprio(0);
    if (nxt)
      WAIT_VM(2);  // retire all but A r1,r3 (read at next tile's phase 2)
    BARRIER();
  }

  // epilogue
#pragma unroll
  for (int j = 0; j < 4; ++j) {
    const int n = n0 + wc * 64 + j * 16 + lane15;
    float bias;
    if (EPI == EPI_QKV)
      bias = (n < E) ? b0[n] : ((n < 2 * E) ? b1f[n - E] : b2f[n - 2 * E]);
    else
      bias = b0[n];
#pragma unroll
    for (int i = 0; i < 8; ++i) {
      const int mr = m0 + wr * 128 + i * 16 + l4 * 4;
      f32x4 v = acc[i][j];
#pragma unroll
      for (int r = 0; r < 4; ++r) {
        const float val = v[r] + bias;
        const int m = mr + r;
        if (EPI == EPI_QKV) {
          if (n < E)            o0[(size_t)m * E + n] = f2bf(val);           // Q [S][E]
          else if (n < 2 * E)   o1[(size_t)m * E + (n - E)] = f2bf(val);     // K [S][E]
          else                  o2[(size_t)(n - 2 * E) * S + m] = f2bf(val); // V^T [H*D][S]
        } else if (EPI == EPI_RELU) {
          o0[(size_t)m * N + n] = f2bf(fmaxf(val, 0.f));
        } else {
          of[(size_t)m * N + n] = val;
        }
      }
    }
  }
}

// ---------------- flash attention v4: BM=128 (32 q-rows/wave), BN=64. ----------------
__global__ __launch_bounds__(256, 2) void flash_attn(const unsigned short* __restrict__ Qb,
                                                     const unsigned short* __restrict__ Kb,
                                                     const unsigned short* __restrict__ VTb,
                                                     unsigned short* __restrict__ attn) {
  const int x = blockIdx.x;                       // 0..31
  const int h = blockIdx.y;                       // 0..15
  const int qt = (h < 8) ? (31 - x) : x;          // paired sizes per CU
  const int qbase = qt * 128;
  const int tid = threadIdx.x, w = tid >> 6, lane = tid & 63;
  const int lane15 = lane & 15, l4 = lane >> 4;
  const int rowb = qbase + w * 32;                // wave's first q row

  __shared__ unsigned short lK[2][64 * 128];   // [s'][d] XOR-swizzled (piece ^= s'&15)
  __shared__ unsigned short lV[2][128 * 64];   // [d][s'] XOR-swizzled (piece ^= d&7)
  __shared__ unsigned short lP[4][16 * 72];    // per-wave P strip, reused by rg=0,1

  bf16x8 aq[2][4];
#pragma unroll
  for (int rg = 0; rg < 2; ++rg) {
    const unsigned short* qrow = Qb + (size_t)(rowb + rg * 16 + lane15) * E + h * DH + l4 * 8;
#pragma unroll
    for (int kk = 0; kk < 4; ++kk) aq[rg][kk] = *(const bf16x8*)(qrow + kk * 32);
  }

  f32x4 zero4 = {0.f, 0.f, 0.f, 0.f};
  f32x4 o[2][8];
  float psum[2][4];
#pragma unroll
  for (int rg = 0; rg < 2; ++rg) {
#pragma unroll
    for (int j = 0; j < 8; ++j) o[rg][j] = zero4;
#pragma unroll
    for (int r = 0; r < 4; ++r) psum[rg][r] = 0.f;
  }

  // prefetch tile 0
  {
#pragma unroll
    for (int i = 0; i < 4; ++i) {
      int c = i * 256 + w * 64 + lane;
      int row = c >> 4, pg = (c & 15) ^ (row & 15);
      async16(Kb + (size_t)row * E + h * DH + pg * 8, &lK[0][(i * 256 + w * 64) * 8]);
    }
#pragma unroll
    for (int i = 0; i < 4; ++i) {
      int c = i * 256 + w * 64 + lane;
      int row = c >> 3, pg = (c & 7) ^ (row & 7);
      async16(VTb + (size_t)(h * DH + row) * S + pg * 8, &lV[0][(i * 256 + w * 64) * 8]);
    }
  }

  const float scale = 0.088388347648318447f;  // 1/sqrt(128)
  const int ktmax = 2 * qt + 1;

  for (int kt = 0; kt <= ktmax; ++kt) {
    __syncthreads();  // drains this tile's loads; safe to overwrite buf (kt+1)&1
    if (kt < ktmax) {  // prefetch next tile into the other buffer (overlaps compute below)
      const int kb2 = (kt + 1) * 64;
      const int nb = (kt + 1) & 1;
#pragma unroll
      for (int i = 0; i < 4; ++i) {
        int c = i * 256 + w * 64 + lane;
        int row = c >> 4, pg = (c & 15) ^ (row & 15);
        async16(Kb + (size_t)(kb2 + row) * E + h * DH + pg * 8, &lK[nb][(i * 256 + w * 64) * 8]);
      }
#pragma unroll
      for (int i = 0; i < 4; ++i) {
        int c = i * 256 + w * 64 + lane;
        int row = c >> 3, pg = (c & 7) ^ (row & 7);
        async16(VTb + (size_t)(h * DH + row) * S + kb2 + pg * 8, &lV[nb][(i * 256 + w * 64) * 8]);
      }
    }
    if (kt * 64 > rowb + 31) continue;  // wave-uniform skip (fully masked tile)
    const int buf = kt & 1;

    // QK^T: 16 lK reads feed 32 MFMAs (both row-groups share each bk)
    f32x4 sacc[2][4];
#pragma unroll
    for (int rg = 0; rg < 2; ++rg)
#pragma unroll
      for (int j = 0; j < 4; ++j) sacc[rg][j] = zero4;
#pragma unroll
    for (int kk = 0; kk < 4; ++kk)
#pragma unroll
      for (int j = 0; j < 4; ++j) {
        int pl = (kk * 4 + l4) ^ lane15;
        bf16x8 bk = *(const bf16x8*)&lK[buf][(j * 16 + lane15) * 128 + pl * 8];
        sacc[0][j] = __builtin_amdgcn_mfma_f32_16x16x32_bf16(aq[0][kk], bk, sacc[0][j], 0, 0, 0);
        sacc[1][j] = __builtin_amdgcn_mfma_f32_16x16x32_bf16(aq[1][kk], bk, sacc[1][j], 0, 0, 0);
      }

    const bool diag = (kt * 64 + 63 > rowb);
    bf16x8 ap[2][2];
#pragma unroll
    for (int rg = 0; rg < 2; ++rg) {
      float p[4][4];
      if (diag) {
#pragma unroll
        for (int j = 0; j < 4; ++j) {
          int col = kt * 64 + j * 16 + lane15;
#pragma unroll
          for (int r = 0; r < 4; ++r) {
            int row = rowb + rg * 16 + l4 * 4 + r;
            p[j][r] = (col <= row) ? __expf(sacc[rg][j][r] * scale) : 0.f;
          }
        }
      } else {
#pragma unroll
        for (int j = 0; j < 4; ++j)
#pragma unroll
          for (int r = 0; r < 4; ++r) p[j][r] = __expf(sacc[rg][j][r] * scale);
      }
#pragma unroll
      for (int r = 0; r < 4; ++r) psum[rg][r] += p[0][r] + p[1][r] + p[2][r] + p[3][r];

#pragma unroll
      for (int j = 0; j < 4; ++j)
#pragma unroll
        for (int r = 0; r < 4; ++r)
          lP[w][(l4 * 4 + r) * 72 + j * 16 + lane15] = f2bf(p[j][r]);

#pragma unroll
      for (int ks = 0; ks < 2; ++ks)
        ap[rg][ks] = *(const bf16x8*)&lP[w][lane15 * 72 + ks * 32 + l4 * 8];
    }

    // PV: 16 lV reads feed 32 MFMAs (both row-groups share each bv)
#pragma unroll
    for (int ks = 0; ks < 2; ++ks)
#pragma unroll
      for (int j = 0; j < 8; ++j) {
        int pl = (ks * 4 + l4) ^ (lane15 & 7);
        bf16x8 bv = *(const bf16x8*)&lV[buf][(j * 16 + lane15) * 64 + pl * 8];
        o[0][j] = __builtin_amdgcn_mfma_f32_16x16x32_bf16(ap[0][ks], bv, o[0][j], 0, 0, 0);
        o[1][j] = __builtin_amdgcn_mfma_f32_16x16x32_bf16(ap[1][ks], bv, o[1][j], 0, 0, 0);
      }
  }

  // deferred row-sum reduction (once): psum over 16 lanes sharing l4
#pragma unroll
  for (int rg = 0; rg < 2; ++rg) {
    float inv[4];
#pragma unroll
    for (int r = 0; r < 4; ++r) {
      float s = psum[rg][r];
#pragma unroll
      for (int off = 1; off < 16; off <<= 1) s += __shfl_xor(s, off, 16);
      inv[r] = 1.0f / s;
    }
#pragma unroll
    for (int j = 0; j < 8; ++j)
#pragma unroll
      for (int r = 0; r < 4; ++r)
        attn[(size_t)(rowb + rg * 16 + l4 * 4 + r) * E + h * DH + j * 16 + lane15] =
            f2bf(o[rg][j][r] * inv[r]);
  }
}

// ---------------- launcher ----------------
extern "C" void kernel_launch(void* const* d_in, const int* in_sizes, int n_in,
                              void* d_out, int out_size, void* d_ws, size_t ws_size,
                              hipStream_t stream) {
  (void)in_sizes; (void)n_in; (void)out_size; (void)ws_size;
  const float* emb = (const float*)d_in[0];
  const float* Wq  = (const float*)d_in[1];
  const float* bq  = (const float*)d_in[2];
  const float* Wk  = (const float*)d_in[3];
  const float* bk  = (const float*)d_in[4];
  const float* Wv  = (const float*)d_in[5];
  const float* bv  = (const float*)d_in[6];
  const float* W1  = (const float*)d_in[7];
  const float* b1  = (const float*)d_in[8];
  const float* W2  = (const float*)d_in[9];
  const float* b2  = (const float*)d_in[10];
  float* out = (float*)d_out;

  // workspace carve (152 MB) with lifetime overlays:
  //   [0,16MB)   emb_bf, reused as attn after QKV GEMM
  //   [16,88MB)  WqkvT(24)+Q(16)+K(16)+V^T(16); overlaid by hidden(64) after flash
  //   [88,120)   W1T    [120,152) W2T
  char* ws = (char*)d_ws;
  const size_t MB = 1024ull * 1024ull;
  unsigned short* embb   = (unsigned short*)(ws);
  unsigned short* attn   = embb;
  char* r1 = ws + 16 * MB;
  unsigned short* WqkvT  = (unsigned short*)(r1);
  unsigned short* Qb     = (unsigned short*)(r1 + 24 * MB);
  unsigned short* Kb     = (unsigned short*)(r1 + 40 * MB);
  unsigned short* VTb    = (unsigned short*)(r1 + 56 * MB);
  unsigned short* hidden = (unsigned short*)(r1);
  unsigned short* W1T    = (unsigned short*)(r1 + 72 * MB);
  unsigned short* W2T    = (unsigned short*)(r1 + 104 * MB);

  dim3 b256(256);
  dim3 b512(512);
  dim3 tb(32, 8);
  cvt_bf16_kernel<<<dim3((S * E) / 1024), b256, 0, stream>>>(emb, embb);
  transpose_cvt<<<dim3(E / 32, E / 32), tb, 0, stream>>>(Wq, WqkvT, E, E);
  transpose_cvt<<<dim3(E / 32, E / 32), tb, 0, stream>>>(Wk, WqkvT + (size_t)E * E, E, E);
  transpose_cvt<<<dim3(E / 32, E / 32), tb, 0, stream>>>(Wv, WqkvT + 2ull * E * E, E, E);
  transpose_cvt<<<dim3(F / 32, E / 32), tb, 0, stream>>>(W1, W1T, E, F);
  transpose_cvt<<<dim3(E / 32, F / 32), tb, 0, stream>>>(W2, W2T, F, E);

  gemm8<EPI_QKV><<<dim3(3 * E / 256, S / 256), b512, 0, stream>>>(
      embb, WqkvT, E, 3 * E, bq, bk, bv, Qb, Kb, VTb, nullptr);
  flash_attn<<<dim3(S / 128, NH), b256, 0, stream>>>(Qb, Kb, VTb, attn);
  gemm8<EPI_RELU><<<dim3(F / 256, S / 256), b512, 0, stream>>>(
      attn, W1T, E, F, b1, nullptr, nullptr, hidden, nullptr, nullptr, nullptr);
  gemm8<EPI_OUT><<<dim3(E / 256, S / 256), b512, 0, stream>>>(
      hidden, W2T, F, E, b2, nullptr, nullptr, nullptr, nullptr, nullptr, out);
}

// Round 4
// 855.708 us; speedup vs baseline: 1.0590x; 1.0590x over previous
//
#include <hip/hip_runtime.h>

typedef __attribute__((ext_vector_type(8))) short bf16x8;
typedef __attribute__((ext_vector_type(4))) float f32x4;

static constexpr int S = 4096;
static constexpr int E = 2048;
static constexpr int F = 8192;
static constexpr int NH = 16;
static constexpr int DH = 128;

__device__ __forceinline__ unsigned short f2bf(float f) {
  unsigned u = __builtin_bit_cast(unsigned, f);
  u += 0x7FFFu + ((u >> 16) & 1u);
  return (unsigned short)(u >> 16);
}

// async global->LDS, 16B per lane. LDS dest = wave-uniform base + lane*16.
__device__ __forceinline__ void async16(const unsigned short* g, unsigned short* l) {
  __builtin_amdgcn_global_load_lds(
      (const __attribute__((address_space(1))) unsigned int*)g,
      (__attribute__((address_space(3))) unsigned int*)l, 16, 0, 0);
}

// Race-proof sync (round-2 lesson): the barrier/waitcnt asm carries a "memory"
// clobber so no ds_read / global_load_lds can be scheduled across a publish
// point. NO sched_barrier(0) and NO forced lgkmcnt(0): ds_reads are
// compiler-visible loads, so the compiler emits fine-grained lgkmcnt(N)
// interleaved with MFMAs (round-3 lesson: forcing a full drain per phase was
// the m141 failure mode, 568 TF).
#define BARRIER() asm volatile("s_barrier" ::: "memory")
#define WAIT_VM(n) asm volatile("s_waitcnt vmcnt(" #n ")" ::: "memory")

// ---------------- elementwise fp32 -> bf16 ----------------
__global__ __launch_bounds__(256) void cvt_bf16_kernel(const float* __restrict__ src,
                                                       unsigned short* __restrict__ dst) {
  int i = (blockIdx.x * 256 + threadIdx.x) * 4;
  float4 v = *(const float4*)(src + i);
  ushort4 o;
  o.x = f2bf(v.x); o.y = f2bf(v.y); o.z = f2bf(v.z); o.w = f2bf(v.w);
  *(ushort4*)(dst + i) = o;
}

// ---------------- transpose + convert: src [R][C] fp32 -> dst [C][R] bf16 ----------------
__global__ __launch_bounds__(256) void transpose_cvt(const float* __restrict__ src,
                                                     unsigned short* __restrict__ dst,
                                                     const int Rr, const int Cc) {
  __shared__ float t[32][33];
  const int c0 = blockIdx.x * 32, r0 = blockIdx.y * 32;
  const int tx = threadIdx.x, ty = threadIdx.y;
#pragma unroll
  for (int i = 0; i < 4; ++i) {
    int r = ty + i * 8;
    t[r][tx] = src[(size_t)(r0 + r) * Cc + c0 + tx];
  }
  __syncthreads();
#pragma unroll
  for (int i = 0; i < 4; ++i) {
    int cr = ty + i * 8;
    dst[(size_t)(c0 + cr) * Rr + r0 + tx] = f2bf(t[tx][cr]);
  }
}

enum { EPI_QKV = 0, EPI_RELU = 1, EPI_OUT = 2 };

// ---------------- GEMM 2-phase 128x128x32 (m97 structure, proven ~200us) ----
// Used for grids that don't shape well at 256^2 (QKV: 384 blocks, OUT: 128).
template <int EPI>
__global__ __launch_bounds__(256) void gemm_bt(
    const unsigned short* __restrict__ A, const unsigned short* __restrict__ B,
    const int K, const int N,
    const float* __restrict__ b0, const float* __restrict__ b1f, const float* __restrict__ b2f,
    unsigned short* __restrict__ o0, unsigned short* __restrict__ o1,
    unsigned short* __restrict__ o2, float* __restrict__ of) {
  __shared__ unsigned short lA[2][128 * 32];
  __shared__ unsigned short lB[2][128 * 32];
  const int tid = threadIdx.x, w = tid >> 6, lane = tid & 63;
  const int lane15 = lane & 15, l4 = lane >> 4;
  const int m0 = blockIdx.y * 128, n0 = blockIdx.x * 128;
  const int wr = w >> 1, wc = w & 1;

  const int u0 = (w * 2 + 0) * 64 + lane;
  const int u1 = (w * 2 + 1) * 64 + lane;
  const unsigned short* gA0 = A + (size_t)(m0 + (u0 >> 2)) * K + (u0 & 3) * 8;
  const unsigned short* gA1 = A + (size_t)(m0 + (u1 >> 2)) * K + (u1 & 3) * 8;
  const unsigned short* gB0 = B + (size_t)(n0 + (u0 >> 2)) * K + (u0 & 3) * 8;
  const unsigned short* gB1 = B + (size_t)(n0 + (u1 >> 2)) * K + (u1 & 3) * 8;
  const int doff0 = (w * 2 + 0) * 512;
  const int doff1 = (w * 2 + 1) * 512;

  f32x4 zero4 = {0.f, 0.f, 0.f, 0.f};
  f32x4 acc[4][4];
#pragma unroll
  for (int i = 0; i < 4; ++i)
#pragma unroll
    for (int j = 0; j < 4; ++j) acc[i][j] = zero4;

  async16(gA0, &lA[0][doff0]);
  async16(gA1, &lA[0][doff1]);
  async16(gB0, &lB[0][doff0]);
  async16(gB1, &lB[0][doff1]);

  for (int ko = 0; ko < K; ko += 32) {
    __syncthreads();
    const int buf = (ko >> 5) & 1;
    if (ko + 32 < K) {
      const int nb = buf ^ 1;
      async16(gA0 + ko + 32, &lA[nb][doff0]);
      async16(gA1 + ko + 32, &lA[nb][doff1]);
      async16(gB0 + ko + 32, &lB[nb][doff0]);
      async16(gB1 + ko + 32, &lB[nb][doff1]);
    }
    bf16x8 av[4], bv[4];
#pragma unroll
    for (int i = 0; i < 4; ++i)
      av[i] = *(const bf16x8*)&lA[buf][(wr * 64 + i * 16 + lane15) * 32 + l4 * 8];
#pragma unroll
    for (int j = 0; j < 4; ++j)
      bv[j] = *(const bf16x8*)&lB[buf][(wc * 64 + j * 16 + lane15) * 32 + l4 * 8];
#pragma unroll
    for (int i = 0; i < 4; ++i)
#pragma unroll
      for (int j = 0; j < 4; ++j)
        acc[i][j] = __builtin_amdgcn_mfma_f32_16x16x32_bf16(av[i], bv[j], acc[i][j], 0, 0, 0);
  }

#pragma unroll
  for (int j = 0; j < 4; ++j) {
    const int n = n0 + wc * 64 + j * 16 + lane15;
    float bias;
    if (EPI == EPI_QKV)
      bias = (n < E) ? b0[n] : ((n < 2 * E) ? b1f[n - E] : b2f[n - 2 * E]);
    else
      bias = b0[n];
#pragma unroll
    for (int i = 0; i < 4; ++i) {
      const int mr = m0 + wr * 64 + i * 16 + l4 * 4;
      f32x4 v = acc[i][j];
#pragma unroll
      for (int r = 0; r < 4; ++r) {
        const float val = v[r] + bias;
        const int m = mr + r;
        if (EPI == EPI_QKV) {
          if (n < E)            o0[(size_t)m * E + n] = f2bf(val);           // Q [S][E]
          else if (n < 2 * E)   o1[(size_t)m * E + (n - E)] = f2bf(val);     // K [S][E]
          else                  o2[(size_t)(n - 2 * E) * S + m] = f2bf(val); // V^T [H*D][S]
        } else if (EPI == EPI_RELU) {
          o0[(size_t)m * N + n] = f2bf(fmaxf(val, 0.f));
        } else {
          of[(size_t)m * N + n] = val;
        }
      }
    }
  }
}

// ---------------- GEMM 256x256x64 4-phase (T2+T3+T4+T5, m201-template port).
// C[M][N] = A[M][K] * B^T[N][K], bf16 in. 512 threads = 8 waves (2M x 4N),
// per-wave 128x64 output = acc[8][4]. LDS 128KB: 2 dbuf x (256x64) x {A,B}.
// XOR piece-swizzle pp = p ^ (row&7): linear DMA dest + pre-swizzled global
// source, swizzled ds_read -> conflict-free b128 reads (verified: 0 conflicts).
// Per K-tile 4 phases, one C-quadrant (16 MFMA) each. Stage order for tile t+1:
//   ph0: B r0,r1   ph1: B r2,r3   ph2: A r0,r2   ph3: A r1,r3
// Per-wave vmcnt ledger (steady state, 2 issues/phase):
//   ph1 queue [A1,A3,B0,B1,B2,B3] -> vmcnt(4) retires A1,A3 (read at ph2);
//   ph3 queue of 8 -> vmcnt(2) retires all but A1,A3 (read at NEXT ph2).
// The barrier AFTER each wait makes the retirement collective (each wave only
// stages 1/8 of every round). lgkm scheduling is left to the compiler.
template <int EPI>
__global__ __launch_bounds__(512, 1) void gemm8(
    const unsigned short* __restrict__ A, const unsigned short* __restrict__ B,
    const int K, const int N,
    const float* __restrict__ b0,
    unsigned short* __restrict__ o0, float* __restrict__ of) {
  __shared__ unsigned short lA[2][256 * 64];
  __shared__ unsigned short lB[2][256 * 64];
  const int tid = threadIdx.x, w = tid >> 6, lane = tid & 63;
  const int lane15 = lane & 15, l4 = lane >> 4;
  const int wr = w >> 2, wc = w & 3;

  // XCD-bijective swizzle, column-chunked: each XCD owns a contiguous strip of
  // N-columns (B panel ~2MB -> L2-resident per XCD). Requires nwg % 8 == 0.
  const int gx = gridDim.x, gy = gridDim.y;
  const int hw = blockIdx.y * gx + blockIdx.x;
  const int chunk = (gx * gy) >> 3;
  const int pos = (hw & 7) * chunk + (hw >> 3);
  const int bx = pos / gy, by = pos % gy;
  const int m0 = by * 256, n0 = bx * 256;

  // staging: thread t covers physical (row = r*64 + (t>>3), piece pp = t&7) of
  // each 64-row round; conceptual piece fetched = pp ^ (row&7) (involution).
  const int prow = tid >> 3;
  const int pcc = (tid & 7) ^ (prow & 7);
  const unsigned short* gA = A + (size_t)(m0 + prow) * K + pcc * 8;
  const unsigned short* gB = B + (size_t)(n0 + prow) * K + pcc * 8;
  const size_t rstep = (size_t)64 * K;  // 64 rows
  const int lw = w * 512;               // wave slice within a 4096-ushort round

  // ds_read swizzled piece index for kk=0,1 (row&7 == lane15&7 for frag rows)
  const int pswz0 = l4 ^ (lane15 & 7);
  const int pswz1 = (4 + l4) ^ (lane15 & 7);
  const int arow = (wr * 128 + lane15) * 64;
  const int brow = (wc * 64 + lane15) * 64;

  f32x4 zero4 = {0.f, 0.f, 0.f, 0.f};
  f32x4 acc[8][4];
#pragma unroll
  for (int i = 0; i < 8; ++i)
#pragma unroll
    for (int j = 0; j < 4; ++j) acc[i][j] = zero4;

  // prologue: stage full tile 0 into buf 0, drain, publish
#pragma unroll
  for (int r = 0; r < 4; ++r) async16(gB + r * rstep, &lB[0][r * 4096 + lw]);
#pragma unroll
  for (int r = 0; r < 4; ++r) async16(gA + r * rstep, &lA[0][r * 4096 + lw]);
  WAIT_VM(0);
  BARRIER();

  const int NT = K >> 6;
  bf16x8 a0[4][2], bb[2][2];
  for (int t = 0; t < NT; ++t) {
    const unsigned short* lAb = lA[t & 1];
    const unsigned short* lBb = lB[t & 1];
    unsigned short* lAn = lA[(t & 1) ^ 1];
    unsigned short* lBn = lB[(t & 1) ^ 1];
    const size_t ko = (size_t)(t + 1) * 64;
    const bool nxt = (t + 1 < NT);

    // ======== phase 0: quadrant (mh=0, nh=0); stage B r0,r1 ========
#pragma unroll
    for (int mi = 0; mi < 4; ++mi) {
      a0[mi][0] = *(const bf16x8*)&lAb[arow + mi * 1024 + pswz0 * 8];
      a0[mi][1] = *(const bf16x8*)&lAb[arow + mi * 1024 + pswz1 * 8];
    }
#pragma unroll
    for (int nj = 0; nj < 2; ++nj) {
      bb[nj][0] = *(const bf16x8*)&lBb[brow + nj * 1024 + pswz0 * 8];
      bb[nj][1] = *(const bf16x8*)&lBb[brow + nj * 1024 + pswz1 * 8];
    }
    if (nxt) {
      async16(gB + 0 * rstep + ko, &lBn[0 * 4096 + lw]);
      async16(gB + 1 * rstep + ko, &lBn[1 * 4096 + lw]);
    }
    BARRIER();
    __builtin_amdgcn_s_setprio(1);
#pragma unroll
    for (int mi = 0; mi < 4; ++mi)
#pragma unroll
      for (int nj = 0; nj < 2; ++nj)
#pragma unroll
        for (int kk = 0; kk < 2; ++kk)
          acc[mi][nj] = __builtin_amdgcn_mfma_f32_16x16x32_bf16(a0[mi][kk], bb[nj][kk], acc[mi][nj], 0, 0, 0);
    __builtin_amdgcn_s_setprio(0);
    BARRIER();

    // ======== phase 1: quadrant (mh=0, nh=1); stage B r2,r3; retire deferred A ========
#pragma unroll
    for (int nj = 0; nj < 2; ++nj) {
      bb[nj][0] = *(const bf16x8*)&lBb[brow + 2048 + nj * 1024 + pswz0 * 8];
      bb[nj][1] = *(const bf16x8*)&lBb[brow + 2048 + nj * 1024 + pswz1 * 8];
    }
    if (nxt) {
      async16(gB + 2 * rstep + ko, &lBn[2 * 4096 + lw]);
      async16(gB + 3 * rstep + ko, &lBn[3 * 4096 + lw]);
    }
    BARRIER();
    __builtin_amdgcn_s_setprio(1);
#pragma unroll
    for (int mi = 0; mi < 4; ++mi)
#pragma unroll
      for (int nj = 0; nj < 2; ++nj)
#pragma unroll
        for (int kk = 0; kk < 2; ++kk)
          acc[mi][2 + nj] = __builtin_amdgcn_mfma_f32_16x16x32_bf16(a0[mi][kk], bb[nj][kk], acc[mi][2 + nj], 0, 0, 0);
    __builtin_amdgcn_s_setprio(0);
    if (nxt)
      WAIT_VM(4);  // retire prev-issued A r1,r3 (read at phase 2)
    else
      WAIT_VM(0);  // final tile: drain leftovers
    BARRIER();

    // ======== phase 2: quadrant (mh=1, nh=0); stage A r0,r2 ========
#pragma unroll
    for (int mi = 0; mi < 4; ++mi) {
      a0[mi][0] = *(const bf16x8*)&lAb[arow + 4096 + mi * 1024 + pswz0 * 8];
      a0[mi][1] = *(const bf16x8*)&lAb[arow + 4096 + mi * 1024 + pswz1 * 8];
    }
#pragma unroll
    for (int nj = 0; nj < 2; ++nj) {
      bb[nj][0] = *(const bf16x8*)&lBb[brow + nj * 1024 + pswz0 * 8];
      bb[nj][1] = *(const bf16x8*)&lBb[brow + nj * 1024 + pswz1 * 8];
    }
    if (nxt) {
      async16(gA + 0 * rstep + ko, &lAn[0 * 4096 + lw]);
      async16(gA + 2 * rstep + ko, &lAn[2 * 4096 + lw]);
    }
    BARRIER();
    __builtin_amdgcn_s_setprio(1);
#pragma unroll
    for (int mi = 0; mi < 4; ++mi)
#pragma unroll
      for (int nj = 0; nj < 2; ++nj)
#pragma unroll
        for (int kk = 0; kk < 2; ++kk)
          acc[4 + mi][nj] = __builtin_amdgcn_mfma_f32_16x16x32_bf16(a0[mi][kk], bb[nj][kk], acc[4 + mi][nj], 0, 0, 0);
    __builtin_amdgcn_s_setprio(0);
    BARRIER();

    // ======== phase 3: quadrant (mh=1, nh=1); stage A r1,r3; boundary wait ========
#pragma unroll
    for (int nj = 0; nj < 2; ++nj) {
      bb[nj][0] = *(const bf16x8*)&lBb[brow + 2048 + nj * 1024 + pswz0 * 8];
      bb[nj][1] = *(const bf16x8*)&lBb[brow + 2048 + nj * 1024 + pswz1 * 8];
    }
    if (nxt) {
      async16(gA + 1 * rstep + ko, &lAn[1 * 4096 + lw]);
      async16(gA + 3 * rstep + ko, &lAn[3 * 4096 + lw]);
    }
    BARRIER();
    __builtin_amdgcn_s_setprio(1);
#pragma unroll
    for (int mi = 0; mi < 4; ++mi)
#pragma unroll
      for (int nj = 0; nj < 2; ++nj)
#pragma unroll
        for (int kk = 0; kk < 2; ++kk)
          acc[4 + mi][2 + nj] = __builtin_amdgcn_mfma_f32_16x16x32_bf16(a0[mi][kk], bb[nj][kk], acc[4 + mi][2 + nj], 0, 0, 0);
    __builtin_amdgcn_s_setprio(0);
    if (nxt)
      WAIT_VM(2);  // retire all but A r1,r3 (read at next tile's phase 2)
    BARRIER();
  }

  // epilogue
#pragma unroll
  for (int j = 0; j < 4; ++j) {
    const int n = n0 + wc * 64 + j * 16 + lane15;
    const float bias = b0[n];
#pragma unroll
    for (int i = 0; i < 8; ++i) {
      const int mr = m0 + wr * 128 + i * 16 + l4 * 4;
      f32x4 v = acc[i][j];
#pragma unroll
      for (int r = 0; r < 4; ++r) {
        const float val = v[r] + bias;
        const int m = mr + r;
        if (EPI == EPI_RELU) {
          o0[(size_t)m * N + n] = f2bf(fmaxf(val, 0.f));
        } else {
          of[(size_t)m * N + n] = val;
        }
      }
    }
  }
}

// ---------------- flash attention v4: BM=128 (32 q-rows/wave), BN=64. ----------------
__global__ __launch_bounds__(256, 2) void flash_attn(const unsigned short* __restrict__ Qb,
                                                     const unsigned short* __restrict__ Kb,
                                                     const unsigned short* __restrict__ VTb,
                                                     unsigned short* __restrict__ attn) {
  const int x = blockIdx.x;                       // 0..31
  const int h = blockIdx.y;                       // 0..15
  const int qt = (h < 8) ? (31 - x) : x;          // paired sizes per CU
  const int qbase = qt * 128;
  const int tid = threadIdx.x, w = tid >> 6, lane = tid & 63;
  const int lane15 = lane & 15, l4 = lane >> 4;
  const int rowb = qbase + w * 32;                // wave's first q row

  __shared__ unsigned short lK[2][64 * 128];   // [s'][d] XOR-swizzled (piece ^= s'&15)
  __shared__ unsigned short lV[2][128 * 64];   // [d][s'] XOR-swizzled (piece ^= d&7)
  __shared__ unsigned short lP[4][16 * 72];    // per-wave P strip, reused by rg=0,1

  bf16x8 aq[2][4];
#pragma unroll
  for (int rg = 0; rg < 2; ++rg) {
    const unsigned short* qrow = Qb + (size_t)(rowb + rg * 16 + lane15) * E + h * DH + l4 * 8;
#pragma unroll
    for (int kk = 0; kk < 4; ++kk) aq[rg][kk] = *(const bf16x8*)(qrow + kk * 32);
  }

  f32x4 zero4 = {0.f, 0.f, 0.f, 0.f};
  f32x4 o[2][8];
  float psum[2][4];
#pragma unroll
  for (int rg = 0; rg < 2; ++rg) {
#pragma unroll
    for (int j = 0; j < 8; ++j) o[rg][j] = zero4;
#pragma unroll
    for (int r = 0; r < 4; ++r) psum[rg][r] = 0.f;
  }

  // prefetch tile 0
  {
#pragma unroll
    for (int i = 0; i < 4; ++i) {
      int c = i * 256 + w * 64 + lane;
      int row = c >> 4, pg = (c & 15) ^ (row & 15);
      async16(Kb + (size_t)row * E + h * DH + pg * 8, &lK[0][(i * 256 + w * 64) * 8]);
    }
#pragma unroll
    for (int i = 0; i < 4; ++i) {
      int c = i * 256 + w * 64 + lane;
      int row = c >> 3, pg = (c & 7) ^ (row & 7);
      async16(VTb + (size_t)(h * DH + row) * S + pg * 8, &lV[0][(i * 256 + w * 64) * 8]);
    }
  }

  const float scale = 0.088388347648318447f;  // 1/sqrt(128)
  const int ktmax = 2 * qt + 1;

  for (int kt = 0; kt <= ktmax; ++kt) {
    __syncthreads();  // drains this tile's loads; safe to overwrite buf (kt+1)&1
    if (kt < ktmax) {  // prefetch next tile into the other buffer (overlaps compute below)
      const int kb2 = (kt + 1) * 64;
      const int nb = (kt + 1) & 1;
#pragma unroll
      for (int i = 0; i < 4; ++i) {
        int c = i * 256 + w * 64 + lane;
        int row = c >> 4, pg = (c & 15) ^ (row & 15);
        async16(Kb + (size_t)(kb2 + row) * E + h * DH + pg * 8, &lK[nb][(i * 256 + w * 64) * 8]);
      }
#pragma unroll
      for (int i = 0; i < 4; ++i) {
        int c = i * 256 + w * 64 + lane;
        int row = c >> 3, pg = (c & 7) ^ (row & 7);
        async16(VTb + (size_t)(h * DH + row) * S + kb2 + pg * 8, &lV[nb][(i * 256 + w * 64) * 8]);
      }
    }
    if (kt * 64 > rowb + 31) continue;  // wave-uniform skip (fully masked tile)
    const int buf = kt & 1;

    // QK^T: 16 lK reads feed 32 MFMAs (both row-groups share each bk)
    f32x4 sacc[2][4];
#pragma unroll
    for (int rg = 0; rg < 2; ++rg)
#pragma unroll
      for (int j = 0; j < 4; ++j) sacc[rg][j] = zero4;
#pragma unroll
    for (int kk = 0; kk < 4; ++kk)
#pragma unroll
      for (int j = 0; j < 4; ++j) {
        int pl = (kk * 4 + l4) ^ lane15;
        bf16x8 bk = *(const bf16x8*)&lK[buf][(j * 16 + lane15) * 128 + pl * 8];
        sacc[0][j] = __builtin_amdgcn_mfma_f32_16x16x32_bf16(aq[0][kk], bk, sacc[0][j], 0, 0, 0);
        sacc[1][j] = __builtin_amdgcn_mfma_f32_16x16x32_bf16(aq[1][kk], bk, sacc[1][j], 0, 0, 0);
      }

    const bool diag = (kt * 64 + 63 > rowb);
    bf16x8 ap[2][2];
#pragma unroll
    for (int rg = 0; rg < 2; ++rg) {
      float p[4][4];
      if (diag) {
#pragma unroll
        for (int j = 0; j < 4; ++j) {
          int col = kt * 64 + j * 16 + lane15;
#pragma unroll
          for (int r = 0; r < 4; ++r) {
            int row = rowb + rg * 16 + l4 * 4 + r;
            p[j][r] = (col <= row) ? __expf(sacc[rg][j][r] * scale) : 0.f;
          }
        }
      } else {
#pragma unroll
        for (int j = 0; j < 4; ++j)
#pragma unroll
          for (int r = 0; r < 4; ++r) p[j][r] = __expf(sacc[rg][j][r] * scale);
      }
#pragma unroll
      for (int r = 0; r < 4; ++r) psum[rg][r] += p[0][r] + p[1][r] + p[2][r] + p[3][r];

#pragma unroll
      for (int j = 0; j < 4; ++j)
#pragma unroll
        for (int r = 0; r < 4; ++r)
          lP[w][(l4 * 4 + r) * 72 + j * 16 + lane15] = f2bf(p[j][r]);

#pragma unroll
      for (int ks = 0; ks < 2; ++ks)
        ap[rg][ks] = *(const bf16x8*)&lP[w][lane15 * 72 + ks * 32 + l4 * 8];
    }

    // PV: 16 lV reads feed 32 MFMAs (both row-groups share each bv)
#pragma unroll
    for (int ks = 0; ks < 2; ++ks)
#pragma unroll
      for (int j = 0; j < 8; ++j) {
        int pl = (ks * 4 + l4) ^ (lane15 & 7);
        bf16x8 bv = *(const bf16x8*)&lV[buf][(j * 16 + lane15) * 64 + pl * 8];
        o[0][j] = __builtin_amdgcn_mfma_f32_16x16x32_bf16(ap[0][ks], bv, o[0][j], 0, 0, 0);
        o[1][j] = __builtin_amdgcn_mfma_f32_16x16x32_bf16(ap[1][ks], bv, o[1][j], 0, 0, 0);
      }
  }

  // deferred row-sum reduction (once): psum over 16 lanes sharing l4
#pragma unroll
  for (int rg = 0; rg < 2; ++rg) {
    float inv[4];
#pragma unroll
    for (int r = 0; r < 4; ++r) {
      float s = psum[rg][r];
#pragma unroll
      for (int off = 1; off < 16; off <<= 1) s += __shfl_xor(s, off, 16);
      inv[r] = 1.0f / s;
    }
#pragma unroll
    for (int j = 0; j < 8; ++j)
#pragma unroll
      for (int r = 0; r < 4; ++r)
        attn[(size_t)(rowb + rg * 16 + l4 * 4 + r) * E + h * DH + j * 16 + lane15] =
            f2bf(o[rg][j][r] * inv[r]);
  }
}

// ---------------- launcher ----------------
extern "C" void kernel_launch(void* const* d_in, const int* in_sizes, int n_in,
                              void* d_out, int out_size, void* d_ws, size_t ws_size,
                              hipStream_t stream) {
  (void)in_sizes; (void)n_in; (void)out_size; (void)ws_size;
  const float* emb = (const float*)d_in[0];
  const float* Wq  = (const float*)d_in[1];
  const float* bq  = (const float*)d_in[2];
  const float* Wk  = (const float*)d_in[3];
  const float* bk  = (const float*)d_in[4];
  const float* Wv  = (const float*)d_in[5];
  const float* bv  = (const float*)d_in[6];
  const float* W1  = (const float*)d_in[7];
  const float* b1  = (const float*)d_in[8];
  const float* W2  = (const float*)d_in[9];
  const float* b2  = (const float*)d_in[10];
  float* out = (float*)d_out;

  // workspace carve (152 MB) with lifetime overlays:
  //   [0,16MB)   emb_bf, reused as attn after QKV GEMM
  //   [16,88MB)  WqkvT(24)+Q(16)+K(16)+V^T(16); overlaid by hidden(64) after flash
  //   [88,120)   W1T    [120,152) W2T
  char* ws = (char*)d_ws;
  const size_t MB = 1024ull * 1024ull;
  unsigned short* embb   = (unsigned short*)(ws);
  unsigned short* attn   = embb;
  char* r1 = ws + 16 * MB;
  unsigned short* WqkvT  = (unsigned short*)(r1);
  unsigned short* Qb     = (unsigned short*)(r1 + 24 * MB);
  unsigned short* Kb     = (unsigned short*)(r1 + 40 * MB);
  unsigned short* VTb    = (unsigned short*)(r1 + 56 * MB);
  unsigned short* hidden = (unsigned short*)(r1);
  unsigned short* W1T    = (unsigned short*)(r1 + 72 * MB);
  unsigned short* W2T    = (unsigned short*)(r1 + 104 * MB);

  dim3 b256(256);
  dim3 b512(512);
  dim3 tb(32, 8);
  cvt_bf16_kernel<<<dim3((S * E) / 1024), b256, 0, stream>>>(emb, embb);
  transpose_cvt<<<dim3(E / 32, E / 32), tb, 0, stream>>>(Wq, WqkvT, E, E);
  transpose_cvt<<<dim3(E / 32, E / 32), tb, 0, stream>>>(Wk, WqkvT + (size_t)E * E, E, E);
  transpose_cvt<<<dim3(E / 32, E / 32), tb, 0, stream>>>(Wv, WqkvT + 2ull * E * E, E, E);
  transpose_cvt<<<dim3(F / 32, E / 32), tb, 0, stream>>>(W1, W1T, E, F);
  transpose_cvt<<<dim3(E / 32, F / 32), tb, 0, stream>>>(W2, W2T, F, E);

  gemm_bt<EPI_QKV><<<dim3(3 * E / 128, S / 128), b256, 0, stream>>>(
      embb, WqkvT, E, 3 * E, bq, bk, bv, Qb, Kb, VTb, nullptr);
  flash_attn<<<dim3(S / 128, NH), b256, 0, stream>>>(Qb, Kb, VTb, attn);
  gemm8<EPI_RELU><<<dim3(F / 256, S / 256), b512, 0, stream>>>(
      attn, W1T, E, F, b1, hidden, nullptr);
  gemm_bt<EPI_OUT><<<dim3(E / 128, S / 128), b256, 0, stream>>>(
      hidden, W2T, F, E, b2, nullptr, nullptr, nullptr, nullptr, nullptr, out);
}

// Round 5
// 839.720 us; speedup vs baseline: 1.0792x; 1.0190x over previous
//
#include <hip/hip_runtime.h>

typedef __attribute__((ext_vector_type(8))) short bf16x8;
typedef __attribute__((ext_vector_type(4))) float f32x4;

static constexpr int S = 4096;
static constexpr int E = 2048;
static constexpr int F = 8192;
static constexpr int NH = 16;
static constexpr int DH = 128;

__device__ __forceinline__ unsigned short f2bf(float f) {
  unsigned u = __builtin_bit_cast(unsigned, f);
  u += 0x7FFFu + ((u >> 16) & 1u);
  return (unsigned short)(u >> 16);
}

// async global->LDS, 16B per lane. LDS dest = wave-uniform base + lane*16.
__device__ __forceinline__ void async16(const unsigned short* g, unsigned short* l) {
  __builtin_amdgcn_global_load_lds(
      (const __attribute__((address_space(1))) unsigned int*)g,
      (__attribute__((address_space(3))) unsigned int*)l, 16, 0, 0);
}

// Race-proof sync (round-2 lesson): barrier/waitcnt asm carries a "memory"
// clobber so no ds_read / global_load_lds moves across a publish point.
// LGKM0 after the barrier (m201 pattern) concentrates each wave's MFMAs into
// a dense burst; NO sched_barrier anywhere (round-3 lesson: order-pinning was
// the m141 failure mode). Correctness never depends on LGKM0 - the ds_reads
// are compiler-visible loads with dataflow-tracked waits.
#define BARRIER() asm volatile("s_barrier" ::: "memory")
#define WAIT_VM(n) asm volatile("s_waitcnt vmcnt(" #n ")" ::: "memory")
#define LGKM0() asm volatile("s_waitcnt lgkmcnt(0)" ::: "memory")

// ---------------- elementwise fp32 -> bf16 ----------------
__global__ __launch_bounds__(256) void cvt_bf16_kernel(const float* __restrict__ src,
                                                       unsigned short* __restrict__ dst) {
  int i = (blockIdx.x * 256 + threadIdx.x) * 4;
  float4 v = *(const float4*)(src + i);
  ushort4 o;
  o.x = f2bf(v.x); o.y = f2bf(v.y); o.z = f2bf(v.z); o.w = f2bf(v.w);
  *(ushort4*)(dst + i) = o;
}

// ---------------- transpose + convert: src [R][C] fp32 -> dst [C][R] bf16.
// 64x64 tile, 256 threads, float4 loads + ushort4 stores (both coalesced);
// LDS [64][65] pad -> max 2-way bank aliasing (free, m136). ----------------
__global__ __launch_bounds__(256) void transpose_cvt(const float* __restrict__ src,
                                                     unsigned short* __restrict__ dst,
                                                     const int Rr, const int Cc) {
  __shared__ float t[64][65];
  const int c0 = blockIdx.x * 64, r0 = blockIdx.y * 64;
  const int tid = threadIdx.x;
  const int lx = tid & 15, ly = tid >> 4;  // 16 float4 per row, 16 rows per pass
#pragma unroll
  for (int p = 0; p < 4; ++p) {
    const int r = p * 16 + ly;
    const float4 v = *(const float4*)(src + (size_t)(r0 + r) * Cc + c0 + lx * 4);
    t[r][lx * 4 + 0] = v.x; t[r][lx * 4 + 1] = v.y;
    t[r][lx * 4 + 2] = v.z; t[r][lx * 4 + 3] = v.w;
  }
  __syncthreads();
#pragma unroll
  for (int p = 0; p < 4; ++p) {
    const int c = p * 16 + ly;  // dst row = source column
    ushort4 o;
    o.x = f2bf(t[lx * 4 + 0][c]);
    o.y = f2bf(t[lx * 4 + 1][c]);
    o.z = f2bf(t[lx * 4 + 2][c]);
    o.w = f2bf(t[lx * 4 + 3][c]);
    *(ushort4*)(dst + (size_t)(c0 + c) * Rr + r0 + lx * 4) = o;
  }
}

enum { EPI_QKV = 0, EPI_RELU = 1, EPI_OUT = 2 };

// ---------------- GEMM 2-phase 128x128x32 (m97 structure, proven ~200us) ----
// Used for grids that don't shape well at 256^2 (QKV: 384 blocks, OUT: 128).
template <int EPI>
__global__ __launch_bounds__(256) void gemm_bt(
    const unsigned short* __restrict__ A, const unsigned short* __restrict__ B,
    const int K, const int N,
    const float* __restrict__ b0, const float* __restrict__ b1f, const float* __restrict__ b2f,
    unsigned short* __restrict__ o0, unsigned short* __restrict__ o1,
    unsigned short* __restrict__ o2, float* __restrict__ of) {
  __shared__ unsigned short lA[2][128 * 32];
  __shared__ unsigned short lB[2][128 * 32];
  const int tid = threadIdx.x, w = tid >> 6, lane = tid & 63;
  const int lane15 = lane & 15, l4 = lane >> 4;
  const int m0 = blockIdx.y * 128, n0 = blockIdx.x * 128;
  const int wr = w >> 1, wc = w & 1;

  const int u0 = (w * 2 + 0) * 64 + lane;
  const int u1 = (w * 2 + 1) * 64 + lane;
  const unsigned short* gA0 = A + (size_t)(m0 + (u0 >> 2)) * K + (u0 & 3) * 8;
  const unsigned short* gA1 = A + (size_t)(m0 + (u1 >> 2)) * K + (u1 & 3) * 8;
  const unsigned short* gB0 = B + (size_t)(n0 + (u0 >> 2)) * K + (u0 & 3) * 8;
  const unsigned short* gB1 = B + (size_t)(n0 + (u1 >> 2)) * K + (u1 & 3) * 8;
  const int doff0 = (w * 2 + 0) * 512;
  const int doff1 = (w * 2 + 1) * 512;

  f32x4 zero4 = {0.f, 0.f, 0.f, 0.f};
  f32x4 acc[4][4];
#pragma unroll
  for (int i = 0; i < 4; ++i)
#pragma unroll
    for (int j = 0; j < 4; ++j) acc[i][j] = zero4;

  async16(gA0, &lA[0][doff0]);
  async16(gA1, &lA[0][doff1]);
  async16(gB0, &lB[0][doff0]);
  async16(gB1, &lB[0][doff1]);

  for (int ko = 0; ko < K; ko += 32) {
    __syncthreads();
    const int buf = (ko >> 5) & 1;
    if (ko + 32 < K) {
      const int nb = buf ^ 1;
      async16(gA0 + ko + 32, &lA[nb][doff0]);
      async16(gA1 + ko + 32, &lA[nb][doff1]);
      async16(gB0 + ko + 32, &lB[nb][doff0]);
      async16(gB1 + ko + 32, &lB[nb][doff1]);
    }
    bf16x8 av[4], bv[4];
#pragma unroll
    for (int i = 0; i < 4; ++i)
      av[i] = *(const bf16x8*)&lA[buf][(wr * 64 + i * 16 + lane15) * 32 + l4 * 8];
#pragma unroll
    for (int j = 0; j < 4; ++j)
      bv[j] = *(const bf16x8*)&lB[buf][(wc * 64 + j * 16 + lane15) * 32 + l4 * 8];
#pragma unroll
    for (int i = 0; i < 4; ++i)
#pragma unroll
      for (int j = 0; j < 4; ++j)
        acc[i][j] = __builtin_amdgcn_mfma_f32_16x16x32_bf16(av[i], bv[j], acc[i][j], 0, 0, 0);
  }

#pragma unroll
  for (int j = 0; j < 4; ++j) {
    const int n = n0 + wc * 64 + j * 16 + lane15;
    float bias;
    if (EPI == EPI_QKV)
      bias = (n < E) ? b0[n] : ((n < 2 * E) ? b1f[n - E] : b2f[n - 2 * E]);
    else
      bias = b0[n];
#pragma unroll
    for (int i = 0; i < 4; ++i) {
      const int mr = m0 + wr * 64 + i * 16 + l4 * 4;
      f32x4 v = acc[i][j];
#pragma unroll
      for (int r = 0; r < 4; ++r) {
        const float val = v[r] + bias;
        const int m = mr + r;
        if (EPI == EPI_QKV) {
          if (n < E)            o0[(size_t)m * E + n] = f2bf(val);           // Q [S][E]
          else if (n < 2 * E)   o1[(size_t)m * E + (n - E)] = f2bf(val);     // K [S][E]
          else                  o2[(size_t)(n - 2 * E) * S + m] = f2bf(val); // V^T [H*D][S]
        } else if (EPI == EPI_RELU) {
          o0[(size_t)m * N + n] = f2bf(fmaxf(val, 0.f));
        } else {
          of[(size_t)m * N + n] = val;
        }
      }
    }
  }
}

// ---------------- GEMM 256x256x64 4-phase (T2+T3+T4+T5, m201-template port).
// Round-5: quadrant order (mh0,nh0)->(mh0,nh1)->(mh1,nh1)->(mh1,nh0) keeps
// both B fragment sets (bb0,bb1) live across the tile -> 24 ds_read_b128 per
// wave per tile (12/4/8/0 per phase) vs 32 before; ph3 is a pure-register
// MFMA burst. LGKM0 after the pre-MFMA barrier (m201-faithful, no
// sched_barrier) makes each wave's 16-MFMA cluster dense so waves slip
// within the phase (the inter-wave LDS/MFMA overlap behind m201's 62%).
// Stage order for tile t+1 (2 async16/phase, unchanged, verified r4):
//   ph0: B r0,r1   ph1: B r2,r3   ph2: A r0,r2   ph3: A r1,r3
// vmcnt ledger (unchanged, verified r4): ph1 end vmcnt(4) retires prev A r1,r3
// (read at ph2); ph3 end vmcnt(2) retires all but A r1,r3 (read at NEXT ph0/2).
template <int EPI>
__global__ __launch_bounds__(512, 1) void gemm8(
    const unsigned short* __restrict__ A, const unsigned short* __restrict__ B,
    const int K, const int N,
    const float* __restrict__ b0,
    unsigned short* __restrict__ o0, float* __restrict__ of) {
  __shared__ unsigned short lA[2][256 * 64];
  __shared__ unsigned short lB[2][256 * 64];
  const int tid = threadIdx.x, w = tid >> 6, lane = tid & 63;
  const int lane15 = lane & 15, l4 = lane >> 4;
  const int wr = w >> 2, wc = w & 3;

  // XCD-bijective swizzle, column-chunked (requires nwg % 8 == 0).
  const int gx = gridDim.x, gy = gridDim.y;
  const int hw = blockIdx.y * gx + blockIdx.x;
  const int chunk = (gx * gy) >> 3;
  const int pos = (hw & 7) * chunk + (hw >> 3);
  const int bx = pos / gy, by = pos % gy;
  const int m0 = by * 256, n0 = bx * 256;

  // staging: thread t covers physical (row = r*64 + (t>>3), piece pp = t&7) of
  // each 64-row round; conceptual piece fetched = pp ^ (row&7) (involution).
  const int prow = tid >> 3;
  const int pcc = (tid & 7) ^ (prow & 7);
  const unsigned short* gA = A + (size_t)(m0 + prow) * K + pcc * 8;
  const unsigned short* gB = B + (size_t)(n0 + prow) * K + pcc * 8;
  const size_t rstep = (size_t)64 * K;  // 64 rows
  const int lw = w * 512;               // wave slice within a 4096-ushort round

  // ds_read swizzled piece index for kk=0,1 (row&7 == lane15&7 for frag rows)
  const int pswz0 = l4 ^ (lane15 & 7);
  const int pswz1 = (4 + l4) ^ (lane15 & 7);
  const int arow = (wr * 128 + lane15) * 64;
  const int brow = (wc * 64 + lane15) * 64;

  f32x4 zero4 = {0.f, 0.f, 0.f, 0.f};
  f32x4 acc[8][4];
#pragma unroll
  for (int i = 0; i < 8; ++i)
#pragma unroll
    for (int j = 0; j < 4; ++j) acc[i][j] = zero4;

  // prologue: stage full tile 0 into buf 0, drain, publish
#pragma unroll
  for (int r = 0; r < 4; ++r) async16(gB + r * rstep, &lB[0][r * 4096 + lw]);
#pragma unroll
  for (int r = 0; r < 4; ++r) async16(gA + r * rstep, &lA[0][r * 4096 + lw]);
  WAIT_VM(0);
  BARRIER();

  const int NT = K >> 6;
  bf16x8 a0[4][2], bb0[2][2], bb1[2][2];
  for (int t = 0; t < NT; ++t) {
    const unsigned short* lAb = lA[t & 1];
    const unsigned short* lBb = lB[t & 1];
    unsigned short* lAn = lA[(t & 1) ^ 1];
    unsigned short* lBn = lB[(t & 1) ^ 1];
    const size_t ko = (size_t)(t + 1) * 64;
    const bool nxt = (t + 1 < NT);

    // ======== phase 0: quadrant (mh=0, nh=0); read A-half0 + B-nh0; stage B r0,r1 ========
#pragma unroll
    for (int mi = 0; mi < 4; ++mi) {
      a0[mi][0] = *(const bf16x8*)&lAb[arow + mi * 1024 + pswz0 * 8];
      a0[mi][1] = *(const bf16x8*)&lAb[arow + mi * 1024 + pswz1 * 8];
    }
#pragma unroll
    for (int nj = 0; nj < 2; ++nj) {
      bb0[nj][0] = *(const bf16x8*)&lBb[brow + nj * 1024 + pswz0 * 8];
      bb0[nj][1] = *(const bf16x8*)&lBb[brow + nj * 1024 + pswz1 * 8];
    }
    if (nxt) {
      async16(gB + 0 * rstep + ko, &lBn[0 * 4096 + lw]);
      async16(gB + 1 * rstep + ko, &lBn[1 * 4096 + lw]);
    }
    BARRIER();
    LGKM0();
    __builtin_amdgcn_s_setprio(1);
#pragma unroll
    for (int mi = 0; mi < 4; ++mi)
#pragma unroll
      for (int nj = 0; nj < 2; ++nj)
#pragma unroll
        for (int kk = 0; kk < 2; ++kk)
          acc[mi][nj] = __builtin_amdgcn_mfma_f32_16x16x32_bf16(a0[mi][kk], bb0[nj][kk], acc[mi][nj], 0, 0, 0);
    __builtin_amdgcn_s_setprio(0);
    BARRIER();

    // ======== phase 1: quadrant (mh=0, nh=1); read B-nh1; stage B r2,r3; retire deferred A ========
#pragma unroll
    for (int nj = 0; nj < 2; ++nj) {
      bb1[nj][0] = *(const bf16x8*)&lBb[brow + 2048 + nj * 1024 + pswz0 * 8];
      bb1[nj][1] = *(const bf16x8*)&lBb[brow + 2048 + nj * 1024 + pswz1 * 8];
    }
    if (nxt) {
      async16(gB + 2 * rstep + ko, &lBn[2 * 4096 + lw]);
      async16(gB + 3 * rstep + ko, &lBn[3 * 4096 + lw]);
    }
    BARRIER();
    LGKM0();
    __builtin_amdgcn_s_setprio(1);
#pragma unroll
    for (int mi = 0; mi < 4; ++mi)
#pragma unroll
      for (int nj = 0; nj < 2; ++nj)
#pragma unroll
        for (int kk = 0; kk < 2; ++kk)
          acc[mi][2 + nj] = __builtin_amdgcn_mfma_f32_16x16x32_bf16(a0[mi][kk], bb1[nj][kk], acc[mi][2 + nj], 0, 0, 0);
    __builtin_amdgcn_s_setprio(0);
    if (nxt)
      WAIT_VM(4);  // retire prev-issued A r1,r3 (read at phase 2)
    else
      WAIT_VM(0);  // final tile: drain leftovers
    BARRIER();

    // ======== phase 2: quadrant (mh=1, nh=1); read A-half1 (reuse bb1); stage A r0,r2 ========
#pragma unroll
    for (int mi = 0; mi < 4; ++mi) {
      a0[mi][0] = *(const bf16x8*)&lAb[arow + 4096 + mi * 1024 + pswz0 * 8];
      a0[mi][1] = *(const bf16x8*)&lAb[arow + 4096 + mi * 1024 + pswz1 * 8];
    }
    if (nxt) {
      async16(gA + 0 * rstep + ko, &lAn[0 * 4096 + lw]);
      async16(gA + 2 * rstep + ko, &lAn[2 * 4096 + lw]);
    }
    BARRIER();
    LGKM0();
    __builtin_amdgcn_s_setprio(1);
#pragma unroll
    for (int mi = 0; mi < 4; ++mi)
#pragma unroll
      for (int nj = 0; nj < 2; ++nj)
#pragma unroll
        for (int kk = 0; kk < 2; ++kk)
          acc[4 + mi][2 + nj] = __builtin_amdgcn_mfma_f32_16x16x32_bf16(a0[mi][kk], bb1[nj][kk], acc[4 + mi][2 + nj], 0, 0, 0);
    __builtin_amdgcn_s_setprio(0);
    BARRIER();

    // ======== phase 3: quadrant (mh=1, nh=0); no reads (reuse a0, bb0); stage A r1,r3 ========
    if (nxt) {
      async16(gA + 1 * rstep + ko, &lAn[1 * 4096 + lw]);
      async16(gA + 3 * rstep + ko, &lAn[3 * 4096 + lw]);
    }
    BARRIER();
    __builtin_amdgcn_s_setprio(1);
#pragma unroll
    for (int mi = 0; mi < 4; ++mi)
#pragma unroll
      for (int nj = 0; nj < 2; ++nj)
#pragma unroll
        for (int kk = 0; kk < 2; ++kk)
          acc[4 + mi][nj] = __builtin_amdgcn_mfma_f32_16x16x32_bf16(a0[mi][kk], bb0[nj][kk], acc[4 + mi][nj], 0, 0, 0);
    __builtin_amdgcn_s_setprio(0);
    if (nxt)
      WAIT_VM(2);  // retire all but A r1,r3 (read at next tile's phase 2)
    BARRIER();
  }

  // epilogue
#pragma unroll
  for (int j = 0; j < 4; ++j) {
    const int n = n0 + wc * 64 + j * 16 + lane15;
    const float bias = b0[n];
#pragma unroll
    for (int i = 0; i < 8; ++i) {
      const int mr = m0 + wr * 128 + i * 16 + l4 * 4;
      f32x4 v = acc[i][j];
#pragma unroll
      for (int r = 0; r < 4; ++r) {
        const float val = v[r] + bias;
        const int m = mr + r;
        if (EPI == EPI_RELU) {
          o0[(size_t)m * N + n] = f2bf(fmaxf(val, 0.f));
        } else {
          of[(size_t)m * N + n] = val;
        }
      }
    }
  }
}

// ---------------- flash attention v4: BM=128 (32 q-rows/wave), BN=64. ----------------
__global__ __launch_bounds__(256, 2) void flash_attn(const unsigned short* __restrict__ Qb,
                                                     const unsigned short* __restrict__ Kb,
                                                     const unsigned short* __restrict__ VTb,
                                                     unsigned short* __restrict__ attn) {
  const int x = blockIdx.x;                       // 0..31
  const int h = blockIdx.y;                       // 0..15
  const int qt = (h < 8) ? (31 - x) : x;          // paired sizes per CU
  const int qbase = qt * 128;
  const int tid = threadIdx.x, w = tid >> 6, lane = tid & 63;
  const int lane15 = lane & 15, l4 = lane >> 4;
  const int rowb = qbase + w * 32;                // wave's first q row

  __shared__ unsigned short lK[2][64 * 128];   // [s'][d] XOR-swizzled (piece ^= s'&15)
  __shared__ unsigned short lV[2][128 * 64];   // [d][s'] XOR-swizzled (piece ^= d&7)
  __shared__ unsigned short lP[4][16 * 72];    // per-wave P strip, reused by rg=0,1

  bf16x8 aq[2][4];
#pragma unroll
  for (int rg = 0; rg < 2; ++rg) {
    const unsigned short* qrow = Qb + (size_t)(rowb + rg * 16 + lane15) * E + h * DH + l4 * 8;
#pragma unroll
    for (int kk = 0; kk < 4; ++kk) aq[rg][kk] = *(const bf16x8*)(qrow + kk * 32);
  }

  f32x4 zero4 = {0.f, 0.f, 0.f, 0.f};
  f32x4 o[2][8];
  float psum[2][4];
#pragma unroll
  for (int rg = 0; rg < 2; ++rg) {
#pragma unroll
    for (int j = 0; j < 8; ++j) o[rg][j] = zero4;
#pragma unroll
    for (int r = 0; r < 4; ++r) psum[rg][r] = 0.f;
  }

  // prefetch tile 0
  {
#pragma unroll
    for (int i = 0; i < 4; ++i) {
      int c = i * 256 + w * 64 + lane;
      int row = c >> 4, pg = (c & 15) ^ (row & 15);
      async16(Kb + (size_t)row * E + h * DH + pg * 8, &lK[0][(i * 256 + w * 64) * 8]);
    }
#pragma unroll
    for (int i = 0; i < 4; ++i) {
      int c = i * 256 + w * 64 + lane;
      int row = c >> 3, pg = (c & 7) ^ (row & 7);
      async16(VTb + (size_t)(h * DH + row) * S + pg * 8, &lV[0][(i * 256 + w * 64) * 8]);
    }
  }

  const float scale = 0.088388347648318447f;  // 1/sqrt(128)
  const int ktmax = 2 * qt + 1;

  for (int kt = 0; kt <= ktmax; ++kt) {
    __syncthreads();  // drains this tile's loads; safe to overwrite buf (kt+1)&1
    if (kt < ktmax) {  // prefetch next tile into the other buffer (overlaps compute below)
      const int kb2 = (kt + 1) * 64;
      const int nb = (kt + 1) & 1;
#pragma unroll
      for (int i = 0; i < 4; ++i) {
        int c = i * 256 + w * 64 + lane;
        int row = c >> 4, pg = (c & 15) ^ (row & 15);
        async16(Kb + (size_t)(kb2 + row) * E + h * DH + pg * 8, &lK[nb][(i * 256 + w * 64) * 8]);
      }
#pragma unroll
      for (int i = 0; i < 4; ++i) {
        int c = i * 256 + w * 64 + lane;
        int row = c >> 3, pg = (c & 7) ^ (row & 7);
        async16(VTb + (size_t)(h * DH + row) * S + kb2 + pg * 8, &lV[nb][(i * 256 + w * 64) * 8]);
      }
    }
    if (kt * 64 > rowb + 31) continue;  // wave-uniform skip (fully masked tile)
    const int buf = kt & 1;

    // QK^T: 16 lK reads feed 32 MFMAs (both row-groups share each bk)
    f32x4 sacc[2][4];
#pragma unroll
    for (int rg = 0; rg < 2; ++rg)
#pragma unroll
      for (int j = 0; j < 4; ++j) sacc[rg][j] = zero4;
#pragma unroll
    for (int kk = 0; kk < 4; ++kk)
#pragma unroll
      for (int j = 0; j < 4; ++j) {
        int pl = (kk * 4 + l4) ^ lane15;
        bf16x8 bk = *(const bf16x8*)&lK[buf][(j * 16 + lane15) * 128 + pl * 8];
        sacc[0][j] = __builtin_amdgcn_mfma_f32_16x16x32_bf16(aq[0][kk], bk, sacc[0][j], 0, 0, 0);
        sacc[1][j] = __builtin_amdgcn_mfma_f32_16x16x32_bf16(aq[1][kk], bk, sacc[1][j], 0, 0, 0);
      }

    const bool diag = (kt * 64 + 63 > rowb);
    bf16x8 ap[2][2];
#pragma unroll
    for (int rg = 0; rg < 2; ++rg) {
      float p[4][4];
      if (diag) {
#pragma unroll
        for (int j = 0; j < 4; ++j) {
          int col = kt * 64 + j * 16 + lane15;
#pragma unroll
          for (int r = 0; r < 4; ++r) {
            int row = rowb + rg * 16 + l4 * 4 + r;
            p[j][r] = (col <= row) ? __expf(sacc[rg][j][r] * scale) : 0.f;
          }
        }
      } else {
#pragma unroll
        for (int j = 0; j < 4; ++j)
#pragma unroll
          for (int r = 0; r < 4; ++r) p[j][r] = __expf(sacc[rg][j][r] * scale);
      }
#pragma unroll
      for (int r = 0; r < 4; ++r) psum[rg][r] += p[0][r] + p[1][r] + p[2][r] + p[3][r];

#pragma unroll
      for (int j = 0; j < 4; ++j)
#pragma unroll
        for (int r = 0; r < 4; ++r)
          lP[w][(l4 * 4 + r) * 72 + j * 16 + lane15] = f2bf(p[j][r]);

#pragma unroll
      for (int ks = 0; ks < 2; ++ks)
        ap[rg][ks] = *(const bf16x8*)&lP[w][lane15 * 72 + ks * 32 + l4 * 8];
    }

    // PV: 16 lV reads feed 32 MFMAs (both row-groups share each bv)
#pragma unroll
    for (int ks = 0; ks < 2; ++ks)
#pragma unroll
      for (int j = 0; j < 8; ++j) {
        int pl = (ks * 4 + l4) ^ (lane15 & 7);
        bf16x8 bv = *(const bf16x8*)&lV[buf][(j * 16 + lane15) * 64 + pl * 8];
        o[0][j] = __builtin_amdgcn_mfma_f32_16x16x32_bf16(ap[0][ks], bv, o[0][j], 0, 0, 0);
        o[1][j] = __builtin_amdgcn_mfma_f32_16x16x32_bf16(ap[1][ks], bv, o[1][j], 0, 0, 0);
      }
  }

  // deferred row-sum reduction (once): psum over 16 lanes sharing l4
#pragma unroll
  for (int rg = 0; rg < 2; ++rg) {
    float inv[4];
#pragma unroll
    for (int r = 0; r < 4; ++r) {
      float s = psum[rg][r];
#pragma unroll
      for (int off = 1; off < 16; off <<= 1) s += __shfl_xor(s, off, 16);
      inv[r] = 1.0f / s;
    }
#pragma unroll
    for (int j = 0; j < 8; ++j)
#pragma unroll
      for (int r = 0; r < 4; ++r)
        attn[(size_t)(rowb + rg * 16 + l4 * 4 + r) * E + h * DH + j * 16 + lane15] =
            f2bf(o[rg][j][r] * inv[r]);
  }
}

// ---------------- launcher ----------------
extern "C" void kernel_launch(void* const* d_in, const int* in_sizes, int n_in,
                              void* d_out, int out_size, void* d_ws, size_t ws_size,
                              hipStream_t stream) {
  (void)in_sizes; (void)n_in; (void)out_size; (void)ws_size;
  const float* emb = (const float*)d_in[0];
  const float* Wq  = (const float*)d_in[1];
  const float* bq  = (const float*)d_in[2];
  const float* Wk  = (const float*)d_in[3];
  const float* bk  = (const float*)d_in[4];
  const float* Wv  = (const float*)d_in[5];
  const float* bv  = (const float*)d_in[6];
  const float* W1  = (const float*)d_in[7];
  const float* b1  = (const float*)d_in[8];
  const float* W2  = (const float*)d_in[9];
  const float* b2  = (const float*)d_in[10];
  float* out = (float*)d_out;

  // workspace carve (152 MB) with lifetime overlays:
  //   [0,16MB)   emb_bf, reused as attn after QKV GEMM
  //   [16,88MB)  WqkvT(24)+Q(16)+K(16)+V^T(16); overlaid by hidden(64) after flash
  //   [88,120)   W1T    [120,152) W2T
  char* ws = (char*)d_ws;
  const size_t MB = 1024ull * 1024ull;
  unsigned short* embb   = (unsigned short*)(ws);
  unsigned short* attn   = embb;
  char* r1 = ws + 16 * MB;
  unsigned short* WqkvT  = (unsigned short*)(r1);
  unsigned short* Qb     = (unsigned short*)(r1 + 24 * MB);
  unsigned short* Kb     = (unsigned short*)(r1 + 40 * MB);
  unsigned short* VTb    = (unsigned short*)(r1 + 56 * MB);
  unsigned short* hidden = (unsigned short*)(r1);
  unsigned short* W1T    = (unsigned short*)(r1 + 72 * MB);
  unsigned short* W2T    = (unsigned short*)(r1 + 104 * MB);

  dim3 b256(256);
  dim3 b512(512);
  cvt_bf16_kernel<<<dim3((S * E) / 1024), b256, 0, stream>>>(emb, embb);
  transpose_cvt<<<dim3(E / 64, E / 64), b256, 0, stream>>>(Wq, WqkvT, E, E);
  transpose_cvt<<<dim3(E / 64, E / 64), b256, 0, stream>>>(Wk, WqkvT + (size_t)E * E, E, E);
  transpose_cvt<<<dim3(E / 64, E / 64), b256, 0, stream>>>(Wv, WqkvT + 2ull * E * E, E, E);
  transpose_cvt<<<dim3(F / 64, E / 64), b256, 0, stream>>>(W1, W1T, E, F);
  transpose_cvt<<<dim3(E / 64, F / 64), b256, 0, stream>>>(W2, W2T, F, E);

  gemm_bt<EPI_QKV><<<dim3(3 * E / 128, S / 128), b256, 0, stream>>>(
      embb, WqkvT, E, 3 * E, bq, bk, bv, Qb, Kb, VTb, nullptr);
  flash_attn<<<dim3(S / 128, NH), b256, 0, stream>>>(Qb, Kb, VTb, attn);
  gemm8<EPI_RELU><<<dim3(F / 256, S / 256), b512, 0, stream>>>(
      attn, W1T, E, F, b1, hidden, nullptr);
  gemm_bt<EPI_OUT><<<dim3(E / 128, S / 128), b256, 0, stream>>>(
      hidden, W2T, F, E, b2, nullptr, nullptr, nullptr, nullptr, nullptr, out);
}

// Round 6
// 837.959 us; speedup vs baseline: 1.0814x; 1.0021x over previous
//
#include <hip/hip_runtime.h>

typedef __attribute__((ext_vector_type(8))) short bf16x8;
typedef __attribute__((ext_vector_type(4))) float f32x4;

static constexpr int S = 4096;
static constexpr int E = 2048;
static constexpr int F = 8192;
static constexpr int NH = 16;
static constexpr int DH = 128;

__device__ __forceinline__ unsigned short f2bf(float f) {
  unsigned u = __builtin_bit_cast(unsigned, f);
  u += 0x7FFFu + ((u >> 16) & 1u);
  return (unsigned short)(u >> 16);
}

// async global->LDS, 16B per lane. LDS dest = wave-uniform base + lane*16.
__device__ __forceinline__ void async16(const unsigned short* g, unsigned short* l) {
  __builtin_amdgcn_global_load_lds(
      (const __attribute__((address_space(1))) unsigned int*)g,
      (__attribute__((address_space(3))) unsigned int*)l, 16, 0, 0);
}

// Race-proof sync (round-2 lesson): barrier/waitcnt asm carries a "memory"
// clobber so no ds_read / global_load_lds moves across a publish point.
// No sched_barrier (round-3 lesson: order-pinning = m141 failure mode).
#define BARRIER() asm volatile("s_barrier" ::: "memory")
#define WAIT_VM(n) asm volatile("s_waitcnt vmcnt(" #n ")" ::: "memory")
#define LGKM0() asm volatile("s_waitcnt lgkmcnt(0)" ::: "memory")

// ---------------- elementwise fp32 -> bf16 ----------------
__global__ __launch_bounds__(256) void cvt_bf16_kernel(const float* __restrict__ src,
                                                       unsigned short* __restrict__ dst) {
  int i = (blockIdx.x * 256 + threadIdx.x) * 4;
  float4 v = *(const float4*)(src + i);
  ushort4 o;
  o.x = f2bf(v.x); o.y = f2bf(v.y); o.z = f2bf(v.z); o.w = f2bf(v.w);
  *(ushort4*)(dst + i) = o;
}

// ---------------- transpose + convert: src [R][C] fp32 -> dst [C][R] bf16.
// 64x64 tile, 256 threads, float4 loads + ushort4 stores (both coalesced);
// LDS [64][65] pad -> max 2-way bank aliasing (free, m136). ----------------
__global__ __launch_bounds__(256) void transpose_cvt(const float* __restrict__ src,
                                                     unsigned short* __restrict__ dst,
                                                     const int Rr, const int Cc) {
  __shared__ float t[64][65];
  const int c0 = blockIdx.x * 64, r0 = blockIdx.y * 64;
  const int tid = threadIdx.x;
  const int lx = tid & 15, ly = tid >> 4;  // 16 float4 per row, 16 rows per pass
#pragma unroll
  for (int p = 0; p < 4; ++p) {
    const int r = p * 16 + ly;
    const float4 v = *(const float4*)(src + (size_t)(r0 + r) * Cc + c0 + lx * 4);
    t[r][lx * 4 + 0] = v.x; t[r][lx * 4 + 1] = v.y;
    t[r][lx * 4 + 2] = v.z; t[r][lx * 4 + 3] = v.w;
  }
  __syncthreads();
#pragma unroll
  for (int p = 0; p < 4; ++p) {
    const int c = p * 16 + ly;  // dst row = source column
    ushort4 o;
    o.x = f2bf(t[lx * 4 + 0][c]);
    o.y = f2bf(t[lx * 4 + 1][c]);
    o.z = f2bf(t[lx * 4 + 2][c]);
    o.w = f2bf(t[lx * 4 + 3][c]);
    *(ushort4*)(dst + (size_t)(c0 + c) * Rr + r0 + lx * 4) = o;
  }
}

enum { EPI_QKV = 0, EPI_RELU = 1, EPI_OUT = 2 };

// ---------------- GEMM 2-phase 128x128x32 (m97 structure, proven ~200us) ----
template <int EPI>
__global__ __launch_bounds__(256) void gemm_bt(
    const unsigned short* __restrict__ A, const unsigned short* __restrict__ B,
    const int K, const int N,
    const float* __restrict__ b0, const float* __restrict__ b1f, const float* __restrict__ b2f,
    unsigned short* __restrict__ o0, unsigned short* __restrict__ o1,
    unsigned short* __restrict__ o2, float* __restrict__ of) {
  __shared__ unsigned short lA[2][128 * 32];
  __shared__ unsigned short lB[2][128 * 32];
  const int tid = threadIdx.x, w = tid >> 6, lane = tid & 63;
  const int lane15 = lane & 15, l4 = lane >> 4;
  const int m0 = blockIdx.y * 128, n0 = blockIdx.x * 128;
  const int wr = w >> 1, wc = w & 1;

  const int u0 = (w * 2 + 0) * 64 + lane;
  const int u1 = (w * 2 + 1) * 64 + lane;
  const unsigned short* gA0 = A + (size_t)(m0 + (u0 >> 2)) * K + (u0 & 3) * 8;
  const unsigned short* gA1 = A + (size_t)(m0 + (u1 >> 2)) * K + (u1 & 3) * 8;
  const unsigned short* gB0 = B + (size_t)(n0 + (u0 >> 2)) * K + (u0 & 3) * 8;
  const unsigned short* gB1 = B + (size_t)(n0 + (u1 >> 2)) * K + (u1 & 3) * 8;
  const int doff0 = (w * 2 + 0) * 512;
  const int doff1 = (w * 2 + 1) * 512;

  f32x4 zero4 = {0.f, 0.f, 0.f, 0.f};
  f32x4 acc[4][4];
#pragma unroll
  for (int i = 0; i < 4; ++i)
#pragma unroll
    for (int j = 0; j < 4; ++j) acc[i][j] = zero4;

  async16(gA0, &lA[0][doff0]);
  async16(gA1, &lA[0][doff1]);
  async16(gB0, &lB[0][doff0]);
  async16(gB1, &lB[0][doff1]);

  for (int ko = 0; ko < K; ko += 32) {
    __syncthreads();
    const int buf = (ko >> 5) & 1;
    if (ko + 32 < K) {
      const int nb = buf ^ 1;
      async16(gA0 + ko + 32, &lA[nb][doff0]);
      async16(gA1 + ko + 32, &lA[nb][doff1]);
      async16(gB0 + ko + 32, &lB[nb][doff0]);
      async16(gB1 + ko + 32, &lB[nb][doff1]);
    }
    bf16x8 av[4], bv[4];
#pragma unroll
    for (int i = 0; i < 4; ++i)
      av[i] = *(const bf16x8*)&lA[buf][(wr * 64 + i * 16 + lane15) * 32 + l4 * 8];
#pragma unroll
    for (int j = 0; j < 4; ++j)
      bv[j] = *(const bf16x8*)&lB[buf][(wc * 64 + j * 16 + lane15) * 32 + l4 * 8];
#pragma unroll
    for (int i = 0; i < 4; ++i)
#pragma unroll
      for (int j = 0; j < 4; ++j)
        acc[i][j] = __builtin_amdgcn_mfma_f32_16x16x32_bf16(av[i], bv[j], acc[i][j], 0, 0, 0);
  }

#pragma unroll
  for (int j = 0; j < 4; ++j) {
    const int n = n0 + wc * 64 + j * 16 + lane15;
    float bias;
    if (EPI == EPI_QKV)
      bias = (n < E) ? b0[n] : ((n < 2 * E) ? b1f[n - E] : b2f[n - 2 * E]);
    else
      bias = b0[n];
#pragma unroll
    for (int i = 0; i < 4; ++i) {
      const int mr = m0 + wr * 64 + i * 16 + l4 * 4;
      f32x4 v = acc[i][j];
#pragma unroll
      for (int r = 0; r < 4; ++r) {
        const float val = v[r] + bias;
        const int m = mr + r;
        if (EPI == EPI_QKV) {
          if (n < E)            o0[(size_t)m * E + n] = f2bf(val);           // Q [S][E]
          else if (n < 2 * E)   o1[(size_t)m * E + (n - E)] = f2bf(val);     // K [S][E]
          else                  o2[(size_t)(n - 2 * E) * S + m] = f2bf(val); // V^T [H*D][S]
        } else if (EPI == EPI_RELU) {
          o0[(size_t)m * N + n] = f2bf(fmaxf(val, 0.f));
        } else {
          of[(size_t)m * N + n] = val;
        }
      }
    }
  }
}

// ---------------- GEMM 256x256x64 4-phase, round-6: DEEP prefetch ledger.
// Phase length ~256 cyc; HBM latency ~900 cyc -> every load needs >=3 phases
// between issue and its counted wait. Old schedule's worst slack was 1.5
// phases (the tile-boundary stall that kept gemm8 at ~720 TF). New issue
// placement (all for tile t+1 except ph3, which pre-stages t+2's B into the
// CURRENT B buffer -- legal since all lB[t&1] reads complete at ph1's
// post-barrier and (t+2)&1 == t&1):
//   ph0: B r2,r3 (t+1)   ph1: A r0,r2 (t+1)   ph2: A r1,r3 (t+1)
//   ph3: B r0,r1 (t+2)
// Waits (FIFO retirement; audited per-tile):
//   ph1-end vmcnt(6): retires A r1,r3 of THIS tile (slack 3.5 ph)
//   ph3-end vmcnt(4): retires B r0-r3 + A r0,r2 of t+1 (min slack 2.5 ph)
// Flight depth 4..10. Tail: p2=false -> ph3-end vmcnt(2); p1=false -> vmcnt(0).
// Prologue: tile0 (8 loads) + B r0,r1 of tile1 -> vmcnt(2).
template <int EPI>
__global__ __launch_bounds__(512, 1) void gemm8(
    const unsigned short* __restrict__ A, const unsigned short* __restrict__ B,
    const int K, const int N,
    const float* __restrict__ b0,
    unsigned short* __restrict__ o0, float* __restrict__ of) {
  __shared__ unsigned short lA[2][256 * 64];
  __shared__ unsigned short lB[2][256 * 64];
  const int tid = threadIdx.x, w = tid >> 6, lane = tid & 63;
  const int lane15 = lane & 15, l4 = lane >> 4;
  const int wr = w >> 2, wc = w & 3;

  // XCD-bijective swizzle, column-chunked (requires nwg % 8 == 0).
  const int gx = gridDim.x, gy = gridDim.y;
  const int hw = blockIdx.y * gx + blockIdx.x;
  const int chunk = (gx * gy) >> 3;
  const int pos = (hw & 7) * chunk + (hw >> 3);
  const int bx = pos / gy, by = pos % gy;
  const int m0 = by * 256, n0 = bx * 256;

  // staging: thread t covers physical (row = r*64 + (t>>3), piece pp = t&7) of
  // each 64-row round; conceptual piece fetched = pp ^ (row&7) (involution).
  const int prow = tid >> 3;
  const int pcc = (tid & 7) ^ (prow & 7);
  const unsigned short* gA = A + (size_t)(m0 + prow) * K + pcc * 8;
  const unsigned short* gB = B + (size_t)(n0 + prow) * K + pcc * 8;
  const size_t rstep = (size_t)64 * K;  // 64 rows
  const int lw = w * 512;               // wave slice within a 4096-ushort round

  // ds_read swizzled piece index for kk=0,1 (row&7 == lane15&7 for frag rows)
  const int pswz0 = l4 ^ (lane15 & 7);
  const int pswz1 = (4 + l4) ^ (lane15 & 7);
  const int arow = (wr * 128 + lane15) * 64;
  const int brow = (wc * 64 + lane15) * 64;

  f32x4 zero4 = {0.f, 0.f, 0.f, 0.f};
  f32x4 acc[8][4];
#pragma unroll
  for (int i = 0; i < 8; ++i)
#pragma unroll
    for (int j = 0; j < 4; ++j) acc[i][j] = zero4;

  const int NT = K >> 6;

  // prologue: tile0 (8 loads) + B r0,r1 of tile1 -> retire tile0, keep 2.
#pragma unroll
  for (int r = 0; r < 4; ++r) async16(gB + r * rstep, &lB[0][r * 4096 + lw]);
#pragma unroll
  for (int r = 0; r < 4; ++r) async16(gA + r * rstep, &lA[0][r * 4096 + lw]);
  async16(gB + 0 * rstep + 64, &lB[1][0 * 4096 + lw]);
  async16(gB + 1 * rstep + 64, &lB[1][1 * 4096 + lw]);
  WAIT_VM(2);
  BARRIER();

  bf16x8 a0[4][2], bb0[2][2], bb1[2][2];
  for (int t = 0; t < NT; ++t) {
    const unsigned short* lAb = lA[t & 1];
    const unsigned short* lBb = lB[t & 1];
    unsigned short* lAn = lA[(t & 1) ^ 1];
    unsigned short* lBn = lB[(t & 1) ^ 1];
    unsigned short* lBc = lB[t & 1];  // t+2's B buffer == current
    const size_t ko1 = (size_t)(t + 1) * 64;
    const size_t ko2 = (size_t)(t + 2) * 64;
    const bool p1 = (t + 1 < NT);
    const bool p2 = (t + 2 < NT);

    // ======== phase 0: quadrant (mh=0, nh=0); stage B r2,r3 (t+1) ========
#pragma unroll
    for (int mi = 0; mi < 4; ++mi) {
      a0[mi][0] = *(const bf16x8*)&lAb[arow + mi * 1024 + pswz0 * 8];
      a0[mi][1] = *(const bf16x8*)&lAb[arow + mi * 1024 + pswz1 * 8];
    }
#pragma unroll
    for (int nj = 0; nj < 2; ++nj) {
      bb0[nj][0] = *(const bf16x8*)&lBb[brow + nj * 1024 + pswz0 * 8];
      bb0[nj][1] = *(const bf16x8*)&lBb[brow + nj * 1024 + pswz1 * 8];
    }
    if (p1) {
      async16(gB + 2 * rstep + ko1, &lBn[2 * 4096 + lw]);
      async16(gB + 3 * rstep + ko1, &lBn[3 * 4096 + lw]);
    }
    BARRIER();
    LGKM0();
    __builtin_amdgcn_s_setprio(1);
#pragma unroll
    for (int mi = 0; mi < 4; ++mi)
#pragma unroll
      for (int nj = 0; nj < 2; ++nj)
#pragma unroll
        for (int kk = 0; kk < 2; ++kk)
          acc[mi][nj] = __builtin_amdgcn_mfma_f32_16x16x32_bf16(a0[mi][kk], bb0[nj][kk], acc[mi][nj], 0, 0, 0);
    __builtin_amdgcn_s_setprio(0);
    BARRIER();

    // ======== phase 1: quadrant (mh=0, nh=1); stage A r0,r2 (t+1) ========
#pragma unroll
    for (int nj = 0; nj < 2; ++nj) {
      bb1[nj][0] = *(const bf16x8*)&lBb[brow + 2048 + nj * 1024 + pswz0 * 8];
      bb1[nj][1] = *(const bf16x8*)&lBb[brow + 2048 + nj * 1024 + pswz1 * 8];
    }
    if (p1) {
      async16(gA + 0 * rstep + ko1, &lAn[0 * 4096 + lw]);
      async16(gA + 2 * rstep + ko1, &lAn[2 * 4096 + lw]);
    }
    BARRIER();
    LGKM0();
    __builtin_amdgcn_s_setprio(1);
#pragma unroll
    for (int mi = 0; mi < 4; ++mi)
#pragma unroll
      for (int nj = 0; nj < 2; ++nj)
#pragma unroll
        for (int kk = 0; kk < 2; ++kk)
          acc[mi][2 + nj] = __builtin_amdgcn_mfma_f32_16x16x32_bf16(a0[mi][kk], bb1[nj][kk], acc[mi][2 + nj], 0, 0, 0);
    __builtin_amdgcn_s_setprio(0);
    if (p1)
      WAIT_VM(6);  // retire A r1,r3 of THIS tile (read next phase); slack 3.5ph
    else
      WAIT_VM(0);  // final tile
    BARRIER();

    // ======== phase 2: quadrant (mh=1, nh=1); stage A r1,r3 (t+1) ========
#pragma unroll
    for (int mi = 0; mi < 4; ++mi) {
      a0[mi][0] = *(const bf16x8*)&lAb[arow + 4096 + mi * 1024 + pswz0 * 8];
      a0[mi][1] = *(const bf16x8*)&lAb[arow + 4096 + mi * 1024 + pswz1 * 8];
    }
    if (p1) {
      async16(gA + 1 * rstep + ko1, &lAn[1 * 4096 + lw]);
      async16(gA + 3 * rstep + ko1, &lAn[3 * 4096 + lw]);
    }
    BARRIER();
    LGKM0();
    __builtin_amdgcn_s_setprio(1);
#pragma unroll
    for (int mi = 0; mi < 4; ++mi)
#pragma unroll
      for (int nj = 0; nj < 2; ++nj)
#pragma unroll
        for (int kk = 0; kk < 2; ++kk)
          acc[4 + mi][2 + nj] = __builtin_amdgcn_mfma_f32_16x16x32_bf16(a0[mi][kk], bb1[nj][kk], acc[4 + mi][2 + nj], 0, 0, 0);
    __builtin_amdgcn_s_setprio(0);
    BARRIER();

    // ======== phase 3: quadrant (mh=1, nh=0); no LDS reads; stage B r0,r1 (t+2)
    // into the CURRENT B buffer (all lB[t&1] reads completed at ph1-post-barrier).
    if (p2) {
      async16(gB + 0 * rstep + ko2, &lBc[0 * 4096 + lw]);
      async16(gB + 1 * rstep + ko2, &lBc[1 * 4096 + lw]);
    }
    BARRIER();
    __builtin_amdgcn_s_setprio(1);
#pragma unroll
    for (int mi = 0; mi < 4; ++mi)
#pragma unroll
      for (int nj = 0; nj < 2; ++nj)
#pragma unroll
        for (int kk = 0; kk < 2; ++kk)
          acc[4 + mi][nj] = __builtin_amdgcn_mfma_f32_16x16x32_bf16(a0[mi][kk], bb0[nj][kk], acc[4 + mi][nj], 0, 0, 0);
    __builtin_amdgcn_s_setprio(0);
    if (p2)
      WAIT_VM(4);  // retire B r0-r3 + A r0,r2 of t+1; keep A r1,r3(t+1)+B r0,r1(t+2)
    else if (p1)
      WAIT_VM(2);  // tail: ph3 issued nothing; keep A r1,r3 of t+1
    else
      WAIT_VM(0);
    BARRIER();
  }

  // epilogue
#pragma unroll
  for (int j = 0; j < 4; ++j) {
    const int n = n0 + wc * 64 + j * 16 + lane15;
    const float bias = b0[n];
#pragma unroll
    for (int i = 0; i < 8; ++i) {
      const int mr = m0 + wr * 128 + i * 16 + l4 * 4;
      f32x4 v = acc[i][j];
#pragma unroll
      for (int r = 0; r < 4; ++r) {
        const float val = v[r] + bias;
        const int m = mr + r;
        if (EPI == EPI_RELU) {
          o0[(size_t)m * N + n] = f2bf(fmaxf(val, 0.f));
        } else {
          of[(size_t)m * N + n] = val;
        }
      }
    }
  }
}

// ---------------- flash attention v4: BM=128 (32 q-rows/wave), BN=64. ----------------
__global__ __launch_bounds__(256, 2) void flash_attn(const unsigned short* __restrict__ Qb,
                                                     const unsigned short* __restrict__ Kb,
                                                     const unsigned short* __restrict__ VTb,
                                                     unsigned short* __restrict__ attn) {
  const int x = blockIdx.x;                       // 0..31
  const int h = blockIdx.y;                       // 0..15
  const int qt = (h < 8) ? (31 - x) : x;          // paired sizes per CU
  const int qbase = qt * 128;
  const int tid = threadIdx.x, w = tid >> 6, lane = tid & 63;
  const int lane15 = lane & 15, l4 = lane >> 4;
  const int rowb = qbase + w * 32;                // wave's first q row

  __shared__ unsigned short lK[2][64 * 128];   // [s'][d] XOR-swizzled (piece ^= s'&15)
  __shared__ unsigned short lV[2][128 * 64];   // [d][s'] XOR-swizzled (piece ^= d&7)
  __shared__ unsigned short lP[4][16 * 72];    // per-wave P strip, reused by rg=0,1

  bf16x8 aq[2][4];
#pragma unroll
  for (int rg = 0; rg < 2; ++rg) {
    const unsigned short* qrow = Qb + (size_t)(rowb + rg * 16 + lane15) * E + h * DH + l4 * 8;
#pragma unroll
    for (int kk = 0; kk < 4; ++kk) aq[rg][kk] = *(const bf16x8*)(qrow + kk * 32);
  }

  f32x4 zero4 = {0.f, 0.f, 0.f, 0.f};
  f32x4 o[2][8];
  float psum[2][4];
#pragma unroll
  for (int rg = 0; rg < 2; ++rg) {
#pragma unroll
    for (int j = 0; j < 8; ++j) o[rg][j] = zero4;
#pragma unroll
    for (int r = 0; r < 4; ++r) psum[rg][r] = 0.f;
  }

  // prefetch tile 0
  {
#pragma unroll
    for (int i = 0; i < 4; ++i) {
      int c = i * 256 + w * 64 + lane;
      int row = c >> 4, pg = (c & 15) ^ (row & 15);
      async16(Kb + (size_t)row * E + h * DH + pg * 8, &lK[0][(i * 256 + w * 64) * 8]);
    }
#pragma unroll
    for (int i = 0; i < 4; ++i) {
      int c = i * 256 + w * 64 + lane;
      int row = c >> 3, pg = (c & 7) ^ (row & 7);
      async16(VTb + (size_t)(h * DH + row) * S + pg * 8, &lV[0][(i * 256 + w * 64) * 8]);
    }
  }

  const float scale = 0.088388347648318447f;  // 1/sqrt(128)
  const int ktmax = 2 * qt + 1;

  for (int kt = 0; kt <= ktmax; ++kt) {
    __syncthreads();  // drains this tile's loads; safe to overwrite buf (kt+1)&1
    if (kt < ktmax) {  // prefetch next tile into the other buffer (overlaps compute below)
      const int kb2 = (kt + 1) * 64;
      const int nb = (kt + 1) & 1;
#pragma unroll
      for (int i = 0; i < 4; ++i) {
        int c = i * 256 + w * 64 + lane;
        int row = c >> 4, pg = (c & 15) ^ (row & 15);
        async16(Kb + (size_t)(kb2 + row) * E + h * DH + pg * 8, &lK[nb][(i * 256 + w * 64) * 8]);
      }
#pragma unroll
      for (int i = 0; i < 4; ++i) {
        int c = i * 256 + w * 64 + lane;
        int row = c >> 3, pg = (c & 7) ^ (row & 7);
        async16(VTb + (size_t)(h * DH + row) * S + kb2 + pg * 8, &lV[nb][(i * 256 + w * 64) * 8]);
      }
    }
    if (kt * 64 > rowb + 31) continue;  // wave-uniform skip (fully masked tile)
    const int buf = kt & 1;

    // QK^T: 16 lK reads feed 32 MFMAs (both row-groups share each bk)
    f32x4 sacc[2][4];
#pragma unroll
    for (int rg = 0; rg < 2; ++rg)
#pragma unroll
      for (int j = 0; j < 4; ++j) sacc[rg][j] = zero4;
#pragma unroll
    for (int kk = 0; kk < 4; ++kk)
#pragma unroll
      for (int j = 0; j < 4; ++j) {
        int pl = (kk * 4 + l4) ^ lane15;
        bf16x8 bk = *(const bf16x8*)&lK[buf][(j * 16 + lane15) * 128 + pl * 8];
        sacc[0][j] = __builtin_amdgcn_mfma_f32_16x16x32_bf16(aq[0][kk], bk, sacc[0][j], 0, 0, 0);
        sacc[1][j] = __builtin_amdgcn_mfma_f32_16x16x32_bf16(aq[1][kk], bk, sacc[1][j], 0, 0, 0);
      }

    const bool diag = (kt * 64 + 63 > rowb);
    bf16x8 ap[2][2];
#pragma unroll
    for (int rg = 0; rg < 2; ++rg) {
      float p[4][4];
      if (diag) {
#pragma unroll
        for (int j = 0; j < 4; ++j) {
          int col = kt * 64 + j * 16 + lane15;
#pragma unroll
          for (int r = 0; r < 4; ++r) {
            int row = rowb + rg * 16 + l4 * 4 + r;
            p[j][r] = (col <= row) ? __expf(sacc[rg][j][r] * scale) : 0.f;
          }
        }
      } else {
#pragma unroll
        for (int j = 0; j < 4; ++j)
#pragma unroll
          for (int r = 0; r < 4; ++r) p[j][r] = __expf(sacc[rg][j][r] * scale);
      }
#pragma unroll
      for (int r = 0; r < 4; ++r) psum[rg][r] += p[0][r] + p[1][r] + p[2][r] + p[3][r];

#pragma unroll
      for (int j = 0; j < 4; ++j)
#pragma unroll
        for (int r = 0; r < 4; ++r)
          lP[w][(l4 * 4 + r) * 72 + j * 16 + lane15] = f2bf(p[j][r]);

#pragma unroll
      for (int ks = 0; ks < 2; ++ks)
        ap[rg][ks] = *(const bf16x8*)&lP[w][lane15 * 72 + ks * 32 + l4 * 8];
    }

    // PV: 16 lV reads feed 32 MFMAs (both row-groups share each bv)
#pragma unroll
    for (int ks = 0; ks < 2; ++ks)
#pragma unroll
      for (int j = 0; j < 8; ++j) {
        int pl = (ks * 4 + l4) ^ (lane15 & 7);
        bf16x8 bv = *(const bf16x8*)&lV[buf][(j * 16 + lane15) * 64 + pl * 8];
        o[0][j] = __builtin_amdgcn_mfma_f32_16x16x32_bf16(ap[0][ks], bv, o[0][j], 0, 0, 0);
        o[1][j] = __builtin_amdgcn_mfma_f32_16x16x32_bf16(ap[1][ks], bv, o[1][j], 0, 0, 0);
      }
  }

  // deferred row-sum reduction (once): psum over 16 lanes sharing l4
#pragma unroll
  for (int rg = 0; rg < 2; ++rg) {
    float inv[4];
#pragma unroll
    for (int r = 0; r < 4; ++r) {
      float s = psum[rg][r];
#pragma unroll
      for (int off = 1; off < 16; off <<= 1) s += __shfl_xor(s, off, 16);
      inv[r] = 1.0f / s;
    }
#pragma unroll
    for (int j = 0; j < 8; ++j)
#pragma unroll
      for (int r = 0; r < 4; ++r)
        attn[(size_t)(rowb + rg * 16 + l4 * 4 + r) * E + h * DH + j * 16 + lane15] =
            f2bf(o[rg][j][r] * inv[r]);
  }
}

// ---------------- launcher ----------------
extern "C" void kernel_launch(void* const* d_in, const int* in_sizes, int n_in,
                              void* d_out, int out_size, void* d_ws, size_t ws_size,
                              hipStream_t stream) {
  (void)in_sizes; (void)n_in; (void)out_size; (void)ws_size;
  const float* emb = (const float*)d_in[0];
  const float* Wq  = (const float*)d_in[1];
  const float* bq  = (const float*)d_in[2];
  const float* Wk  = (const float*)d_in[3];
  const float* bk  = (const float*)d_in[4];
  const float* Wv  = (const float*)d_in[5];
  const float* bv  = (const float*)d_in[6];
  const float* W1  = (const float*)d_in[7];
  const float* b1  = (const float*)d_in[8];
  const float* W2  = (const float*)d_in[9];
  const float* b2  = (const float*)d_in[10];
  float* out = (float*)d_out;

  // workspace carve (152 MB) with lifetime overlays:
  //   [0,16MB)   emb_bf, reused as attn after QKV GEMM
  //   [16,88MB)  WqkvT(24)+Q(16)+K(16)+V^T(16); overlaid by hidden(64) after flash
  //   [88,120)   W1T    [120,152) W2T
  char* ws = (char*)d_ws;
  const size_t MB = 1024ull * 1024ull;
  unsigned short* embb   = (unsigned short*)(ws);
  unsigned short* attn   = embb;
  char* r1 = ws + 16 * MB;
  unsigned short* WqkvT  = (unsigned short*)(r1);
  unsigned short* Qb     = (unsigned short*)(r1 + 24 * MB);
  unsigned short* Kb     = (unsigned short*)(r1 + 40 * MB);
  unsigned short* VTb    = (unsigned short*)(r1 + 56 * MB);
  unsigned short* hidden = (unsigned short*)(r1);
  unsigned short* W1T    = (unsigned short*)(r1 + 72 * MB);
  unsigned short* W2T    = (unsigned short*)(r1 + 104 * MB);

  dim3 b256(256);
  dim3 b512(512);
  cvt_bf16_kernel<<<dim3((S * E) / 1024), b256, 0, stream>>>(emb, embb);
  transpose_cvt<<<dim3(E / 64, E / 64), b256, 0, stream>>>(Wq, WqkvT, E, E);
  transpose_cvt<<<dim3(E / 64, E / 64), b256, 0, stream>>>(Wk, WqkvT + (size_t)E * E, E, E);
  transpose_cvt<<<dim3(E / 64, E / 64), b256, 0, stream>>>(Wv, WqkvT + 2ull * E * E, E, E);
  transpose_cvt<<<dim3(F / 64, E / 64), b256, 0, stream>>>(W1, W1T, E, F);
  transpose_cvt<<<dim3(E / 64, F / 64), b256, 0, stream>>>(W2, W2T, F, E);

  gemm_bt<EPI_QKV><<<dim3(3 * E / 128, S / 128), b256, 0, stream>>>(
      embb, WqkvT, E, 3 * E, bq, bk, bv, Qb, Kb, VTb, nullptr);
  flash_attn<<<dim3(S / 128, NH), b256, 0, stream>>>(Qb, Kb, VTb, attn);
  gemm8<EPI_RELU><<<dim3(F / 256, S / 256), b512, 0, stream>>>(
      attn, W1T, E, F, b1, hidden, nullptr);
  gemm_bt<EPI_OUT><<<dim3(E / 128, S / 128), b256, 0, stream>>>(
      hidden, W2T, F, E, b2, nullptr, nullptr, nullptr, nullptr, nullptr, out);
}